// Round 6
// baseline (282.405 us; speedup 1.0000x reference)
//
#include <hip/hip_runtime.h>
#include <hip/hip_bf16.h>
#include <math.h>

using u16x8  = __attribute__((ext_vector_type(8))) unsigned short;
using bf16x8 = __attribute__((ext_vector_type(8))) __bf16;
using f32x4  = __attribute__((ext_vector_type(4))) float;

#define HP 66
#define C_ 256
#define K_ 2304

static __device__ __forceinline__ float bu2f(unsigned short u) {
  unsigned int v = ((unsigned int)u) << 16;
  return __builtin_bit_cast(float, v);
}
static __device__ __forceinline__ unsigned short f2bu(float f) {
  return __builtin_bit_cast(unsigned short, (__bf16)f);
}
static __device__ __forceinline__ void glds16(const unsigned short* g, unsigned short* l) {
  __builtin_amdgcn_global_load_lds((const __attribute__((address_space(1))) void*)g,
                                   (__attribute__((address_space(3))) void*)l, 16, 0, 0);
}

// ---------------- Kernel 1: transpose x (B,C,H,W) fp32 -> padded channels-last bf16 (B,66,66,C)
__global__ __launch_bounds__(256) void k_transpose(const float* __restrict__ x,
                                                   unsigned short* __restrict__ xTp) {
  __shared__ float tile[64][65];
  int blk = blockIdx.x;
  int b   = blk >> 8;
  int rem = blk & 255;
  int cblk = rem >> 6;
  int h    = rem & 63;
  int c0   = cblk * 64;
  int t  = threadIdx.x;
  int tw = t & 63;
  int tg = t >> 6;
  const u16x8 kz = {0, 0, 0, 0, 0, 0, 0, 0};
  const float* xb = x + (((size_t)(b * C_ + c0)) << 12) + (h << 6);
#pragma unroll
  for (int p = 0; p < 16; ++p) {
    int cl = p * 4 + tg;
    tile[cl][tw] = xb[((size_t)cl << 12) + tw];
  }
  if (t < 16) {
    int colb = (t & 8) ? 65 : 0;
    unsigned short* zp = xTp + (((size_t)(b * HP + h + 1)) * HP + colb) * C_ + c0 + ((t & 7) << 3);
    *reinterpret_cast<u16x8*>(zp) = kz;
  }
  if (h == 0) {
    for (int i = t; i < 2 * 66 * 8; i += 256) {
      int rsel = (i >= 528) ? 1 : 0;
      int j = i - rsel * 528;
      int col = j >> 3, c8 = (j & 7) << 3;
      unsigned short* zp = xTp + (((size_t)(b * HP + rsel * 65)) * HP + col) * C_ + c0 + c8;
      *reinterpret_cast<u16x8*>(zp) = kz;
    }
  }
  __syncthreads();
  unsigned short* dst = xTp + (((size_t)(b * HP + h + 1)) * HP + 1) * C_ + c0;
#pragma unroll
  for (int p = 0; p < 16; ++p) {
    int wl = p * 4 + tg;
    dst[(size_t)wl * C_ + tw] = f2bu(tile[tw][wl]);
  }
}

// ---------------- Kernel 2: weight/bn prep (wT stored pre-swizzled for LDS slot-XOR)
__global__ void k_prep(const float* __restrict__ w_dloc, const float* __restrict__ w_dcla,
                       const float* __restrict__ w_locx, const float* __restrict__ w_clax,
                       const float* __restrict__ g_loc, const float* __restrict__ be_loc,
                       const float* __restrict__ m_loc, const float* __restrict__ v_loc,
                       const float* __restrict__ g_cla, const float* __restrict__ be_cla,
                       const float* __restrict__ m_cla, const float* __restrict__ v_cla,
                       const float* __restrict__ b_locx, const float* __restrict__ b_clax,
                       const float* __restrict__ w_om, const float* __restrict__ w_conf,
                       unsigned short* __restrict__ wT, unsigned short* __restrict__ W2t,
                       unsigned short* __restrict__ wB,
                       float* __restrict__ bnA, float* __restrict__ bnB,
                       float* __restrict__ bias2) {
  int idx = blockIdx.x * blockDim.x + threadIdx.x;
  const int NWT = 512 * K_;
  const int NW2 = 80 * 512;
  const int NWB = 48 * 256;
  if (idx < NWT) {
    int o    = idx / K_;
    int rest = idx - o * K_;
    int kp   = rest >> 8;
    int cq   = rest & 255;
    int q    = cq >> 6;
    int chp  = cq & 63;
    int sp   = chp >> 3;
    int e    = chp & 7;
    int c    = (q << 6) | ((sp ^ (o & 7)) << 3) | e;   // slot-XOR pre-swizzle
    float v = (o < 256) ? w_dloc[(o * 256 + c) * 9 + kp]
                        : w_dcla[((o - 256) * 256 + c) * 9 + kp];
    wT[idx] = f2bu(v);
  } else if (idx < NWT + NW2) {
    int i2 = idx - NWT;
    int j  = i2 >> 9;
    int c2 = i2 & 511;
    float v = 0.f;
    if (j < 24) { if (c2 < 256) v = w_locx[j * 256 + c2]; }
    else if (j < 69) { if (c2 >= 256) v = w_clax[(j - 24) * 256 + (c2 - 256)]; }
    W2t[i2] = f2bu(v);
  } else if (idx < NWT + NW2 + NWB) {
    int i3 = idx - NWT - NW2;
    int j  = i3 >> 8;
    int c  = i3 & 255;
    float v = 0.f;
    if (j < 27) v = w_om[j * 256 + c];
    else if (j < 33) v = w_conf[(j - 27) * 256 + c];
    wB[i3] = f2bu(v);
  } else if (idx < NWT + NW2 + NWB + 512) {
    int o = idx - NWT - NW2 - NWB;
    float s, sh;
    if (o < 256) { s = g_loc[o] / sqrtf(v_loc[o] + 1e-5f); sh = be_loc[o] - m_loc[o] * s; }
    else { int o2 = o - 256; s = g_cla[o2] / sqrtf(v_cla[o2] + 1e-5f); sh = be_cla[o2] - m_cla[o2] * s; }
    bnA[o] = s; bnB[o] = sh;
  } else if (idx < NWT + NW2 + NWB + 512 + 80) {
    int j = idx - NWT - NW2 - NWB - 512;
    float v = 0.f;
    if (j < 24) v = b_locx[j];
    else if (j < 69) v = b_clax[j - 24];
    bias2[j] = v;
  }
}

// ---------------- Kernel 3: MFMA 1x1 conv (M=32768,N=48,K=256) -> conf + gather records
__global__ __launch_bounds__(256) void k_offsets(const unsigned short* __restrict__ xTp,
    const unsigned short* __restrict__ wB,
    const float* __restrict__ b_om, const float* __restrict__ b_conf,
    unsigned int* __restrict__ rec_i, float4* __restrict__ rec_w,
    float* __restrict__ out) {
  __shared__ unsigned short As[128 * 40];
  __shared__ unsigned short Bs[48 * 40];
  __shared__ float P[128 * 49];
  const int tid  = threadIdx.x;
  const int lane = tid & 63;
  const int wv   = tid >> 6;
  const int m0   = blockIdx.x * 128;
  const int b    = m0 >> 12;
  f32x4 acc[2][3] = {};
  for (int ks = 0; ks < 8; ++ks) {
#pragma unroll
    for (int u = 0; u < 2; ++u) {
      int un = u * 256 + tid;
      int px = un >> 2;
      int c8 = (un & 3) << 3;
      int m  = m0 + px;
      int h  = (m & 4095) >> 6, w = m & 63;
      const unsigned short* src = xTp + (((size_t)(b * HP + h + 1)) * HP + w + 1) * C_ + ks * 32 + c8;
      *reinterpret_cast<u16x8*>(&As[px * 40 + c8]) = *reinterpret_cast<const u16x8*>(src);
    }
    if (tid < 192) {
      int j = tid >> 2, c8 = (tid & 3) << 3;
      *reinterpret_cast<u16x8*>(&Bs[j * 40 + c8]) =
          *reinterpret_cast<const u16x8*>(&wB[j * 256 + ks * 32 + c8]);
    }
    __syncthreads();
    int kb = (lane >> 4) << 3;
    bf16x8 af[2];
#pragma unroll
    for (int mf = 0; mf < 2; ++mf)
      af[mf] = *reinterpret_cast<const bf16x8*>(&As[(wv * 32 + mf * 16 + (lane & 15)) * 40 + kb]);
#pragma unroll
    for (int nf = 0; nf < 3; ++nf) {
      bf16x8 bfr = *reinterpret_cast<const bf16x8*>(&Bs[(nf * 16 + (lane & 15)) * 40 + kb]);
#pragma unroll
      for (int mf = 0; mf < 2; ++mf)
        acc[mf][nf] = __builtin_amdgcn_mfma_f32_16x16x32_bf16(af[mf], bfr, acc[mf][nf], 0, 0, 0);
    }
    __syncthreads();
  }
#pragma unroll
  for (int mf = 0; mf < 2; ++mf)
#pragma unroll
    for (int nf = 0; nf < 3; ++nf)
#pragma unroll
      for (int jj = 0; jj < 4; ++jj)
        P[(wv * 32 + mf * 16 + ((lane >> 4) << 2) + jj) * 49 + nf * 16 + (lane & 15)] = acc[mf][nf][jj];
  __syncthreads();
  if (tid < 128) {
    int px = tid;
    int m  = m0 + px;
    int hw = m & 4095;
    int h = hw >> 6, w = hw & 63;
    const float* row = &P[px * 49];
#pragma unroll
    for (int j = 0; j < 6; ++j) {
      float v = row[27 + j] + b_conf[j];
      int a = j >> 1, ch = 8 + (j & 1);
      out[(((size_t)(b * 3 + a)) * 25 + ch) * 4096 + hw] = v;
    }
#pragma unroll
    for (int k = 0; k < 9; ++k) {
      float o1 = row[k] + b_om[k];
      float o2 = row[9 + k] + b_om[9 + k];
      float mz = row[18 + k] + b_om[18 + k];
      float mk = 1.f / (1.f + __expf(-mz));
      float pr = (float)(h + k / 3) + o1;
      float pc = (float)(w + k % 3) + o2;
      pr = fminf(fmaxf(pr, 0.f), 65.f);
      pc = fminf(fmaxf(pc, 0.f), 65.f);
      int r0 = (int)floorf(pr);
      int c0 = (int)floorf(pc);
      int r1 = min(r0 + 1, 65);
      int c1 = min(c0 + 1, 65);
      float ar = 1.f + (float)r0 - pr;
      float br = 1.f - ((float)r1 - pr);
      float ac = 1.f + (float)c0 - pc;
      float bc = 1.f - ((float)c1 - pc);
      int ridx = m * 9 + k;
      rec_i[ridx] = (unsigned)r0 | ((unsigned)c0 << 8) | ((unsigned)r1 << 16) | ((unsigned)c1 << 24);
      rec_w[ridx] = make_float4(ar * ac * mk, br * bc * mk, ar * bc * mk, br * ac * mk);
    }
  }
}

// ---------------- Kernel 4: fused gather + dual deform-conv GEMM
// Tile 128x256, 512 blocks (2 blocks/CU), acc[4][4]=64 AGPR, 80 KB LDS,
// taps confined to write phase (no cross-MFMA liveness), counted vmcnt.
__global__ __launch_bounds__(512, 4) void k_deform_gemm(
    const unsigned short* __restrict__ xTp, const unsigned short* __restrict__ wT,
    const unsigned int* __restrict__ rec_i, const float4* __restrict__ rec_w,
    const float* __restrict__ bnA, const float* __restrict__ bnB,
    unsigned short* __restrict__ y) {
  __shared__ unsigned short Asl[128 * 64];      // 16 KB
  __shared__ unsigned short Bsl[2][256 * 64];   // 64 KB
  const int tid   = threadIdx.x;
  const int bid   = blockIdx.x;
  const int img   = bid & 7;            // image per XCD
  const int inner = bid >> 3;           // 0..63
  const int n0    = (inner & 1) << 8;   // 0 or 256
  const int m0    = (img << 12) + (inner >> 1) * 128;
  const int lane  = tid & 63;
  const int wid   = tid >> 6;
  const int wm    = wid >> 2;           // 0..1
  const int wn    = wid & 3;            // 0..3
  f32x4 acc[4][4] = {};
  const unsigned short* xb = xTp + (size_t)img * (HP * HP * C_);

  // A staging: px = tid>>2 (0..127), two ch-chunks c2a / c2b (same px -> same taps addrs)
  const int px  = tid >> 2;
  const int c2a = tid & 3;
  const int c2b = 4 + (tid & 3);
  const int rbase = (m0 + px) * 9;
  // B staging: wave wid stages rows n0+wid*32 .. +31
  const unsigned short* wrow = wT + (size_t)(n0 + wid * 32 + (lane >> 3)) * K_ + (lane & 7) * 8;

  float4 rw;
  int offc[4];

#define GLDS_B(NP, SS) do { \
  _Pragma("unroll") \
  for (int i = 0; i < 4; ++i) \
    glds16(wrow + (SS) * 64 + (size_t)i * 8 * K_, (unsigned short*)&Bsl[NP][(wid * 32 + i * 8) * 64]); \
} while (0)

#define WRITE_A(S) do { \
  if (((S) & 3) == 0) { \
    unsigned int ri = rec_i[rbase + ((S) >> 2)]; \
    rw = rec_w[rbase + ((S) >> 2)]; \
    int r0 = ri & 255, c0v = (ri >> 8) & 255, r1 = (ri >> 16) & 255, c1v = ri >> 24; \
    offc[0] = (r0 * 66 + c0v) << 8; offc[1] = (r1 * 66 + c1v) << 8; \
    offc[2] = (r0 * 66 + c1v) << 8; offc[3] = (r1 * 66 + c0v) << 8; \
  } \
  const unsigned short* bq_ = xb + (((S) & 3) << 6); \
  u16x8 tA0 = *reinterpret_cast<const u16x8*>(bq_ + offc[0] + (c2a << 3)); \
  u16x8 tA1 = *reinterpret_cast<const u16x8*>(bq_ + offc[1] + (c2a << 3)); \
  u16x8 tA2 = *reinterpret_cast<const u16x8*>(bq_ + offc[2] + (c2a << 3)); \
  u16x8 tA3 = *reinterpret_cast<const u16x8*>(bq_ + offc[3] + (c2a << 3)); \
  u16x8 tB0 = *reinterpret_cast<const u16x8*>(bq_ + offc[0] + (c2b << 3)); \
  u16x8 tB1 = *reinterpret_cast<const u16x8*>(bq_ + offc[1] + (c2b << 3)); \
  u16x8 tB2 = *reinterpret_cast<const u16x8*>(bq_ + offc[2] + (c2b << 3)); \
  u16x8 tB3 = *reinterpret_cast<const u16x8*>(bq_ + offc[3] + (c2b << 3)); \
  u16x8 oa, ob; \
  _Pragma("unroll") \
  for (int j = 0; j < 8; ++j) { \
    float va = rw.x * bu2f(tA0[j]) + rw.y * bu2f(tA1[j]) + rw.z * bu2f(tA2[j]) + rw.w * bu2f(tA3[j]); \
    oa[j] = f2bu(va); \
  } \
  *reinterpret_cast<u16x8*>(&Asl[px * 64 + ((c2a ^ (px & 7)) << 3)]) = oa; \
  _Pragma("unroll") \
  for (int j = 0; j < 8; ++j) { \
    float vb = rw.x * bu2f(tB0[j]) + rw.y * bu2f(tB1[j]) + rw.z * bu2f(tB2[j]) + rw.w * bu2f(tB3[j]); \
    ob[j] = f2bu(vb); \
  } \
  *reinterpret_cast<u16x8*>(&Asl[px * 64 + ((c2b ^ (px & 7)) << 3)]) = ob; \
} while (0)

#define MFMA_K(P, ksub) do { \
  const int sl = (ksub) * 4 + (lane >> 4); \
  const int ps = (sl ^ (lane & 7)) << 3; \
  bf16x8 af[4]; \
  _Pragma("unroll") \
  for (int mf = 0; mf < 4; ++mf) \
    af[mf] = *reinterpret_cast<const bf16x8*>(&Asl[(wm * 64 + mf * 16 + (lane & 15)) * 64 + ps]); \
  _Pragma("unroll") \
  for (int nf = 0; nf < 4; ++nf) { \
    bf16x8 bfr = *reinterpret_cast<const bf16x8*>(&Bsl[P][(wn * 64 + nf * 16 + (lane & 15)) * 64 + ps]); \
    _Pragma("unroll") \
    for (int mf = 0; mf < 4; ++mf) \
      acc[mf][nf] = __builtin_amdgcn_mfma_f32_16x16x32_bf16(af[mf], bfr, acc[mf][nf], 0, 0, 0); \
  } \
} while (0)

#define STEP_BODY(S, P, NP) do { \
  __builtin_amdgcn_sched_barrier(0); \
  __builtin_amdgcn_s_barrier(); \
  __builtin_amdgcn_sched_barrier(0); \
  WRITE_A(S); \
  __builtin_amdgcn_sched_barrier(0); \
  if ((S) < 35) GLDS_B(NP, (S) + 1); \
  __builtin_amdgcn_sched_barrier(0); \
  if ((S) < 35) asm volatile("s_waitcnt vmcnt(4) lgkmcnt(0)" ::: "memory"); \
  else          asm volatile("s_waitcnt vmcnt(0) lgkmcnt(0)" ::: "memory"); \
  __builtin_amdgcn_sched_barrier(0); \
  __builtin_amdgcn_s_barrier(); \
  __builtin_amdgcn_sched_barrier(0); \
  __builtin_amdgcn_s_setprio(1); \
  MFMA_K(P, 0); \
  MFMA_K(P, 1); \
  __builtin_amdgcn_s_setprio(0); \
} while (0)

  // ---- prologue: issue B(0)
  GLDS_B(0, 0);

  // ---- main loop: 36 steps, parity-unrolled x2 (Bsl parity = s&1)
  for (int t2 = 0; t2 < 18; ++t2) {
    STEP_BODY(2 * t2, 0, 1);
    STEP_BODY(2 * t2 + 1, 1, 0);
  }

  // ---- epilogue: BN + LeakyReLU -> y (bf16, [m][512])
#pragma unroll
  for (int nf = 0; nf < 4; ++nf) {
    int o = n0 + wn * 64 + nf * 16 + (lane & 15);
    float sc = bnA[o], sh = bnB[o];
#pragma unroll
    for (int mf = 0; mf < 4; ++mf) {
#pragma unroll
      for (int j = 0; j < 4; ++j) {
        int row = wm * 64 + mf * 16 + ((lane >> 4) << 2) + j;
        float v = acc[mf][nf][j] * sc + sh;
        v = (v >= 0.f) ? v : 0.01f * v;
        y[(size_t)(m0 + row) * 512 + o] = f2bu(v);
      }
    }
  }
#undef GLDS_B
#undef WRITE_A
#undef MFMA_K
#undef STEP_BODY
}

// ---------------- Kernel 5: final 1x1 convs (K=512 block-diagonal, N=69) + scatter
__global__ __launch_bounds__(256) void k_final(const unsigned short* __restrict__ y,
    const unsigned short* __restrict__ W2t, const float* __restrict__ bias2,
    float* __restrict__ out) {
  __shared__ unsigned short As[64 * 40];
  __shared__ unsigned short Bs[80 * 40];
  int tid  = threadIdx.x;
  int lane = tid & 63;
  int wid  = tid >> 6;
  int m0   = blockIdx.x * 64;
  f32x4 acc[5] = {};
  for (int ksv = 0; ksv < 16; ++ksv) {
    __syncthreads();
    {
      int px = tid >> 2;
      int ch = (tid & 3) << 3;
      u16x8 v = *reinterpret_cast<const u16x8*>(y + (size_t)(m0 + px) * 512 + ksv * 32 + ch);
      *reinterpret_cast<u16x8*>(&As[px * 40 + ch]) = v;
    }
    {
      int j = tid >> 2, ch = (tid & 3) << 3;
      u16x8 v = *reinterpret_cast<const u16x8*>(W2t + (size_t)j * 512 + ksv * 32 + ch);
      *reinterpret_cast<u16x8*>(&Bs[j * 40 + ch]) = v;
      if (tid < 64) {
        int un = 256 + tid;
        int j2 = un >> 2, c2 = (un & 3) << 3;
        u16x8 v2 = *reinterpret_cast<const u16x8*>(W2t + (size_t)j2 * 512 + ksv * 32 + c2);
        *reinterpret_cast<u16x8*>(&Bs[j2 * 40 + c2]) = v2;
      }
    }
    __syncthreads();
    bf16x8 af = *reinterpret_cast<const bf16x8*>(&As[(wid * 16 + (lane & 15)) * 40 + ((lane >> 4) << 3)]);
#pragma unroll
    for (int nf = 0; nf < 5; ++nf) {
      bf16x8 bfr = *reinterpret_cast<const bf16x8*>(&Bs[(nf * 16 + (lane & 15)) * 40 + ((lane >> 4) << 3)]);
      acc[nf] = __builtin_amdgcn_mfma_f32_16x16x32_bf16(af, bfr, acc[nf], 0, 0, 0);
    }
  }
#pragma unroll
  for (int nf = 0; nf < 5; ++nf) {
    int j = nf * 16 + (lane & 15);
    if (j < 69) {
      float bs = bias2[j];
      int a, ch2;
      if (j < 24) { a = j >> 3; ch2 = j & 7; }
      else { int jj = j - 24; a = jj / 15; ch2 = 10 + (jj % 15); }
#pragma unroll
      for (int q = 0; q < 4; ++q) {
        int m  = m0 + wid * 16 + ((lane >> 4) << 2) + q;
        int bb = m >> 12, hw = m & 4095;
        out[(((size_t)(bb * 3 + a)) * 25 + ch2) * 4096 + hw] = acc[nf][q] + bs;
      }
    }
  }
}

extern "C" void kernel_launch(void* const* d_in, const int* in_sizes, int n_in,
                              void* d_out, int out_size, void* d_ws, size_t ws_size,
                              hipStream_t stream) {
  const float* x      = (const float*)d_in[0];
  const float* w_conf = (const float*)d_in[1];
  const float* b_conf = (const float*)d_in[2];
  const float* w_om   = (const float*)d_in[3];
  const float* b_om   = (const float*)d_in[4];
  const float* w_dloc = (const float*)d_in[5];
  const float* g_loc  = (const float*)d_in[6];
  const float* be_loc = (const float*)d_in[7];
  const float* m_loc  = (const float*)d_in[8];
  const float* v_loc  = (const float*)d_in[9];
  const float* w_locx = (const float*)d_in[10];
  const float* b_locx = (const float*)d_in[11];
  const float* w_dcla = (const float*)d_in[12];
  const float* g_cla  = (const float*)d_in[13];
  const float* be_cla = (const float*)d_in[14];
  const float* m_cla  = (const float*)d_in[15];
  const float* v_cla  = (const float*)d_in[16];
  const float* w_clax = (const float*)d_in[17];
  const float* b_clax = (const float*)d_in[18];
  float* out = (float*)d_out;

  char* ws = (char*)d_ws;
  size_t off = 0;
  unsigned short* xTp = (unsigned short*)(ws + off); off += (size_t)8 * HP * HP * C_ * 2;
  unsigned short* wT  = (unsigned short*)(ws + off); off += (size_t)512 * K_ * 2;
  unsigned short* W2t = (unsigned short*)(ws + off); off += (size_t)80 * 512 * 2;
  unsigned short* wB  = (unsigned short*)(ws + off); off += (size_t)48 * 256 * 2;
  float* bnA   = (float*)(ws + off); off += 512 * 4;
  float* bnB   = (float*)(ws + off); off += 512 * 4;
  float* bias2 = (float*)(ws + off); off += 128 * 4;
  unsigned int* rec_i = (unsigned int*)(ws + off); off += (size_t)294912 * 4;
  float4* rec_w       = (float4*)(ws + off);       off += (size_t)294912 * 16;
  unsigned short* y   = (unsigned short*)(ws + off); off += (size_t)32768 * 512 * 2;

  k_transpose<<<2048, 256, 0, stream>>>(x, xTp);
  {
    int total = 512 * K_ + 80 * 512 + 48 * 256 + 512 + 80;
    k_prep<<<(total + 255) / 256, 256, 0, stream>>>(w_dloc, w_dcla, w_locx, w_clax,
        g_loc, be_loc, m_loc, v_loc, g_cla, be_cla, m_cla, v_cla, b_locx, b_clax,
        w_om, w_conf, wT, W2t, wB, bnA, bnB, bias2);
  }
  k_offsets<<<256, 256, 0, stream>>>(xTp, wB, b_om, b_conf, rec_i, rec_w, out);
  k_deform_gemm<<<512, 512, 0, stream>>>(xTp, wT, rec_i, rec_w, bnA, bnB, y);
  k_final<<<512, 256, 0, stream>>>(y, W2t, bias2, out);
}

// Round 7
// 209.528 us; speedup vs baseline: 1.3478x; 1.3478x over previous
//
#include <hip/hip_runtime.h>
#include <hip/hip_bf16.h>
#include <math.h>

using u16x8  = __attribute__((ext_vector_type(8))) unsigned short;
using bf16x8 = __attribute__((ext_vector_type(8))) __bf16;
using f32x4  = __attribute__((ext_vector_type(4))) float;

#define HP 66
#define C_ 256
#define K_ 2304

static __device__ __forceinline__ float bu2f(unsigned short u) {
  unsigned int v = ((unsigned int)u) << 16;
  return __builtin_bit_cast(float, v);
}
static __device__ __forceinline__ unsigned short f2bu(float f) {
  return __builtin_bit_cast(unsigned short, (__bf16)f);
}
static __device__ __forceinline__ void glds16(const unsigned short* g, unsigned short* l) {
  __builtin_amdgcn_global_load_lds((const __attribute__((address_space(1))) void*)g,
                                   (__attribute__((address_space(3))) void*)l, 16, 0, 0);
}

// ---------------- Kernel 1: transpose x (B,C,H,W) fp32 -> padded channels-last bf16 (B,66,66,C)
__global__ __launch_bounds__(256) void k_transpose(const float* __restrict__ x,
                                                   unsigned short* __restrict__ xTp) {
  __shared__ float tile[64][65];
  int blk = blockIdx.x;
  int b   = blk >> 8;
  int rem = blk & 255;
  int cblk = rem >> 6;
  int h    = rem & 63;
  int c0   = cblk * 64;
  int t  = threadIdx.x;
  int tw = t & 63;
  int tg = t >> 6;
  const u16x8 kz = {0, 0, 0, 0, 0, 0, 0, 0};
  const float* xb = x + (((size_t)(b * C_ + c0)) << 12) + (h << 6);
#pragma unroll
  for (int p = 0; p < 16; ++p) {
    int cl = p * 4 + tg;
    tile[cl][tw] = xb[((size_t)cl << 12) + tw];
  }
  if (t < 16) {
    int colb = (t & 8) ? 65 : 0;
    unsigned short* zp = xTp + (((size_t)(b * HP + h + 1)) * HP + colb) * C_ + c0 + ((t & 7) << 3);
    *reinterpret_cast<u16x8*>(zp) = kz;
  }
  if (h == 0) {
    for (int i = t; i < 2 * 66 * 8; i += 256) {
      int rsel = (i >= 528) ? 1 : 0;
      int j = i - rsel * 528;
      int col = j >> 3, c8 = (j & 7) << 3;
      unsigned short* zp = xTp + (((size_t)(b * HP + rsel * 65)) * HP + col) * C_ + c0 + c8;
      *reinterpret_cast<u16x8*>(zp) = kz;
    }
  }
  __syncthreads();
  unsigned short* dst = xTp + (((size_t)(b * HP + h + 1)) * HP + 1) * C_ + c0;
#pragma unroll
  for (int p = 0; p < 16; ++p) {
    int wl = p * 4 + tg;
    dst[(size_t)wl * C_ + tw] = f2bu(tile[tw][wl]);
  }
}

// ---------------- Kernel 2: weight/bn prep (wT stored pre-swizzled for LDS slot-XOR)
__global__ void k_prep(const float* __restrict__ w_dloc, const float* __restrict__ w_dcla,
                       const float* __restrict__ w_locx, const float* __restrict__ w_clax,
                       const float* __restrict__ g_loc, const float* __restrict__ be_loc,
                       const float* __restrict__ m_loc, const float* __restrict__ v_loc,
                       const float* __restrict__ g_cla, const float* __restrict__ be_cla,
                       const float* __restrict__ m_cla, const float* __restrict__ v_cla,
                       const float* __restrict__ b_locx, const float* __restrict__ b_clax,
                       const float* __restrict__ w_om, const float* __restrict__ w_conf,
                       unsigned short* __restrict__ wT, unsigned short* __restrict__ W2t,
                       unsigned short* __restrict__ wB,
                       float* __restrict__ bnA, float* __restrict__ bnB,
                       float* __restrict__ bias2) {
  int idx = blockIdx.x * blockDim.x + threadIdx.x;
  const int NWT = 512 * K_;
  const int NW2 = 80 * 512;
  const int NWB = 48 * 256;
  if (idx < NWT) {
    int o    = idx / K_;
    int rest = idx - o * K_;
    int kp   = rest >> 8;
    int cq   = rest & 255;
    int q    = cq >> 6;
    int chp  = cq & 63;
    int sp   = chp >> 3;
    int e    = chp & 7;
    int c    = (q << 6) | ((sp ^ (o & 7)) << 3) | e;   // slot-XOR pre-swizzle
    float v = (o < 256) ? w_dloc[(o * 256 + c) * 9 + kp]
                        : w_dcla[((o - 256) * 256 + c) * 9 + kp];
    wT[idx] = f2bu(v);
  } else if (idx < NWT + NW2) {
    int i2 = idx - NWT;
    int j  = i2 >> 9;
    int c2 = i2 & 511;
    float v = 0.f;
    if (j < 24) { if (c2 < 256) v = w_locx[j * 256 + c2]; }
    else if (j < 69) { if (c2 >= 256) v = w_clax[(j - 24) * 256 + (c2 - 256)]; }
    W2t[i2] = f2bu(v);
  } else if (idx < NWT + NW2 + NWB) {
    int i3 = idx - NWT - NW2;
    int j  = i3 >> 8;
    int c  = i3 & 255;
    float v = 0.f;
    if (j < 27) v = w_om[j * 256 + c];
    else if (j < 33) v = w_conf[(j - 27) * 256 + c];
    wB[i3] = f2bu(v);
  } else if (idx < NWT + NW2 + NWB + 512) {
    int o = idx - NWT - NW2 - NWB;
    float s, sh;
    if (o < 256) { s = g_loc[o] / sqrtf(v_loc[o] + 1e-5f); sh = be_loc[o] - m_loc[o] * s; }
    else { int o2 = o - 256; s = g_cla[o2] / sqrtf(v_cla[o2] + 1e-5f); sh = be_cla[o2] - m_cla[o2] * s; }
    bnA[o] = s; bnB[o] = sh;
  } else if (idx < NWT + NW2 + NWB + 512 + 80) {
    int j = idx - NWT - NW2 - NWB - 512;
    float v = 0.f;
    if (j < 24) v = b_locx[j];
    else if (j < 69) v = b_clax[j - 24];
    bias2[j] = v;
  }
}

// ---------------- Kernel 3: MFMA 1x1 conv (M=32768,N=48,K=256) -> conf + gather records
__global__ __launch_bounds__(256) void k_offsets(const unsigned short* __restrict__ xTp,
    const unsigned short* __restrict__ wB,
    const float* __restrict__ b_om, const float* __restrict__ b_conf,
    unsigned int* __restrict__ rec_i, float4* __restrict__ rec_w,
    float* __restrict__ out) {
  __shared__ unsigned short As[128 * 40];
  __shared__ unsigned short Bs[48 * 40];
  __shared__ float P[128 * 49];
  const int tid  = threadIdx.x;
  const int lane = tid & 63;
  const int wv   = tid >> 6;
  const int m0   = blockIdx.x * 128;
  const int b    = m0 >> 12;
  f32x4 acc[2][3] = {};
  for (int ks = 0; ks < 8; ++ks) {
#pragma unroll
    for (int u = 0; u < 2; ++u) {
      int un = u * 256 + tid;
      int px = un >> 2;
      int c8 = (un & 3) << 3;
      int m  = m0 + px;
      int h  = (m & 4095) >> 6, w = m & 63;
      const unsigned short* src = xTp + (((size_t)(b * HP + h + 1)) * HP + w + 1) * C_ + ks * 32 + c8;
      *reinterpret_cast<u16x8*>(&As[px * 40 + c8]) = *reinterpret_cast<const u16x8*>(src);
    }
    if (tid < 192) {
      int j = tid >> 2, c8 = (tid & 3) << 3;
      *reinterpret_cast<u16x8*>(&Bs[j * 40 + c8]) =
          *reinterpret_cast<const u16x8*>(&wB[j * 256 + ks * 32 + c8]);
    }
    __syncthreads();
    int kb = (lane >> 4) << 3;
    bf16x8 af[2];
#pragma unroll
    for (int mf = 0; mf < 2; ++mf)
      af[mf] = *reinterpret_cast<const bf16x8*>(&As[(wv * 32 + mf * 16 + (lane & 15)) * 40 + kb]);
#pragma unroll
    for (int nf = 0; nf < 3; ++nf) {
      bf16x8 bfr = *reinterpret_cast<const bf16x8*>(&Bs[(nf * 16 + (lane & 15)) * 40 + kb]);
#pragma unroll
      for (int mf = 0; mf < 2; ++mf)
        acc[mf][nf] = __builtin_amdgcn_mfma_f32_16x16x32_bf16(af[mf], bfr, acc[mf][nf], 0, 0, 0);
    }
    __syncthreads();
  }
#pragma unroll
  for (int mf = 0; mf < 2; ++mf)
#pragma unroll
    for (int nf = 0; nf < 3; ++nf)
#pragma unroll
      for (int jj = 0; jj < 4; ++jj)
        P[(wv * 32 + mf * 16 + ((lane >> 4) << 2) + jj) * 49 + nf * 16 + (lane & 15)] = acc[mf][nf][jj];
  __syncthreads();
  if (tid < 128) {
    int px = tid;
    int m  = m0 + px;
    int hw = m & 4095;
    int h = hw >> 6, w = hw & 63;
    const float* row = &P[px * 49];
#pragma unroll
    for (int j = 0; j < 6; ++j) {
      float v = row[27 + j] + b_conf[j];
      int a = j >> 1, ch = 8 + (j & 1);
      out[(((size_t)(b * 3 + a)) * 25 + ch) * 4096 + hw] = v;
    }
#pragma unroll
    for (int k = 0; k < 9; ++k) {
      float o1 = row[k] + b_om[k];
      float o2 = row[9 + k] + b_om[9 + k];
      float mz = row[18 + k] + b_om[18 + k];
      float mk = 1.f / (1.f + __expf(-mz));
      float pr = (float)(h + k / 3) + o1;
      float pc = (float)(w + k % 3) + o2;
      pr = fminf(fmaxf(pr, 0.f), 65.f);
      pc = fminf(fmaxf(pc, 0.f), 65.f);
      int r0 = (int)floorf(pr);
      int c0 = (int)floorf(pc);
      int r1 = min(r0 + 1, 65);
      int c1 = min(c0 + 1, 65);
      float ar = 1.f + (float)r0 - pr;
      float br = 1.f - ((float)r1 - pr);
      float ac = 1.f + (float)c0 - pc;
      float bc = 1.f - ((float)c1 - pc);
      int ridx = m * 9 + k;
      rec_i[ridx] = (unsigned)r0 | ((unsigned)c0 << 8) | ((unsigned)r1 << 16) | ((unsigned)c1 << 24);
      rec_w[ridx] = make_float4(ar * ac * mk, br * bc * mk, ar * bc * mk, br * ac * mk);
    }
  }
}

// ---------------- Kernel 4: fused gather + dual deform-conv GEMM
// 4-wave blocks, tile 64x128, acc[2][4]=32 AGPR, 40 KB LDS -> 3-4 blocks/CU.
// Cross-block asynchrony hides the gather/lerp chain; no spill by construction.
__global__ __launch_bounds__(256, 3) void k_deform_gemm(
    const unsigned short* __restrict__ xTp, const unsigned short* __restrict__ wT,
    const unsigned int* __restrict__ rec_i, const float4* __restrict__ rec_w,
    const float* __restrict__ bnA, const float* __restrict__ bnB,
    unsigned short* __restrict__ y) {
  __shared__ unsigned short Asl[64 * 64];       // 8 KB
  __shared__ unsigned short Bsl[2][128 * 64];   // 32 KB
  const int tid   = threadIdx.x;
  const int bid   = blockIdx.x;
  const int img   = bid & 7;           // image per XCD
  const int inner = bid >> 3;          // 0..255
  const int mrow  = inner >> 2;        // 0..63
  const int n0    = (inner & 3) << 7;  // 0,128,256,384
  const int m0    = (img << 12) + (mrow << 6);
  const int lane  = tid & 63;
  const int wid   = tid >> 6;          // 0..3
  const int wm    = wid >> 1;          // 0..1
  const int wn    = wid & 1;           // 0..1
  f32x4 acc[2][4] = {};
  const unsigned short* xb = xTp + (size_t)img * (HP * HP * C_);

  // A staging (round-2 proven conflict-free shape): pxq = tid>>3, slot = tid&7
  const int pxq = tid >> 3;                        // 0..31
  const int chx = (((tid & 7) ^ (pxq & 7)) << 3);  // pre-swizzled global chunk
  const int rb0 = (m0 + pxq) * 9;
  const int rb1 = (m0 + 32 + pxq) * 9;
  // B staging: wave wid stages rows n0+wid*32 .. +31
  const unsigned short* wrow = wT + (size_t)(n0 + wid * 32 + (lane >> 3)) * K_ + (lane & 7) * 8;

  float4 rw0, rw1;
  int offc0[4], offc1[4];

#define GLDS_B(NP, SS) do { \
  _Pragma("unroll") \
  for (int i = 0; i < 4; ++i) \
    glds16(wrow + (SS) * 64 + (size_t)i * 8 * K_, (unsigned short*)&Bsl[NP][(wid * 32 + i * 8) * 64]); \
} while (0)

#define LOAD_REC(KP) do { \
  unsigned int ri0 = rec_i[rb0 + (KP)]; \
  unsigned int ri1 = rec_i[rb1 + (KP)]; \
  rw0 = rec_w[rb0 + (KP)]; \
  rw1 = rec_w[rb1 + (KP)]; \
  { int r0 = ri0 & 255, c0v = (ri0 >> 8) & 255, r1 = (ri0 >> 16) & 255, c1v = ri0 >> 24; \
    offc0[0] = (r0 * 66 + c0v) << 8; offc0[1] = (r1 * 66 + c1v) << 8; \
    offc0[2] = (r0 * 66 + c1v) << 8; offc0[3] = (r1 * 66 + c0v) << 8; } \
  { int r0 = ri1 & 255, c0v = (ri1 >> 8) & 255, r1 = (ri1 >> 16) & 255, c1v = ri1 >> 24; \
    offc1[0] = (r0 * 66 + c0v) << 8; offc1[1] = (r1 * 66 + c1v) << 8; \
    offc1[2] = (r0 * 66 + c1v) << 8; offc1[3] = (r1 * 66 + c0v) << 8; } \
} while (0)

#define WRITE_A(S) do { \
  if (((S) & 3) == 0) LOAD_REC((S) >> 2); \
  const unsigned short* bq_ = xb + (((S) & 3) << 6) + chx; \
  u16x8 t00 = *reinterpret_cast<const u16x8*>(bq_ + offc0[0]); \
  u16x8 t01 = *reinterpret_cast<const u16x8*>(bq_ + offc0[1]); \
  u16x8 t02 = *reinterpret_cast<const u16x8*>(bq_ + offc0[2]); \
  u16x8 t03 = *reinterpret_cast<const u16x8*>(bq_ + offc0[3]); \
  u16x8 t10 = *reinterpret_cast<const u16x8*>(bq_ + offc1[0]); \
  u16x8 t11 = *reinterpret_cast<const u16x8*>(bq_ + offc1[1]); \
  u16x8 t12 = *reinterpret_cast<const u16x8*>(bq_ + offc1[2]); \
  u16x8 t13 = *reinterpret_cast<const u16x8*>(bq_ + offc1[3]); \
  u16x8 o0, o1; \
  _Pragma("unroll") \
  for (int j = 0; j < 8; ++j) { \
    float v = rw0.x * bu2f(t00[j]) + rw0.y * bu2f(t01[j]) \
            + rw0.z * bu2f(t02[j]) + rw0.w * bu2f(t03[j]); \
    o0[j] = f2bu(v); \
  } \
  *reinterpret_cast<u16x8*>(&Asl[pxq * 64 + ((tid & 7) << 3)]) = o0; \
  _Pragma("unroll") \
  for (int j = 0; j < 8; ++j) { \
    float v = rw1.x * bu2f(t10[j]) + rw1.y * bu2f(t11[j]) \
            + rw1.z * bu2f(t12[j]) + rw1.w * bu2f(t13[j]); \
    o1[j] = f2bu(v); \
  } \
  *reinterpret_cast<u16x8*>(&Asl[(32 + pxq) * 64 + ((tid & 7) << 3)]) = o1; \
} while (0)

#define MFMA_K(P, ksub) do { \
  const int sl = (ksub) * 4 + (lane >> 4); \
  const int ps = (sl ^ (lane & 7)) << 3; \
  bf16x8 af[2]; \
  _Pragma("unroll") \
  for (int mf = 0; mf < 2; ++mf) \
    af[mf] = *reinterpret_cast<const bf16x8*>(&Asl[(wm * 32 + mf * 16 + (lane & 15)) * 64 + ps]); \
  _Pragma("unroll") \
  for (int nf = 0; nf < 4; ++nf) { \
    bf16x8 bfr = *reinterpret_cast<const bf16x8*>(&Bsl[P][(wn * 64 + nf * 16 + (lane & 15)) * 64 + ps]); \
    _Pragma("unroll") \
    for (int mf = 0; mf < 2; ++mf) \
      acc[mf][nf] = __builtin_amdgcn_mfma_f32_16x16x32_bf16(af[mf], bfr, acc[mf][nf], 0, 0, 0); \
  } \
} while (0)

#define STEP_BODY(S, P, NP) do { \
  __builtin_amdgcn_s_barrier();  /* A + Bsl[NP] free (prev MFMA done) */ \
  __builtin_amdgcn_sched_barrier(0); \
  WRITE_A(S); \
  __builtin_amdgcn_sched_barrier(0); \
  if ((S) < 35) GLDS_B(NP, (S) + 1); \
  __builtin_amdgcn_sched_barrier(0); \
  if ((S) < 35) asm volatile("s_waitcnt vmcnt(4) lgkmcnt(0)" ::: "memory"); \
  else          asm volatile("s_waitcnt vmcnt(0) lgkmcnt(0)" ::: "memory"); \
  __builtin_amdgcn_s_barrier(); \
  __builtin_amdgcn_sched_barrier(0); \
  __builtin_amdgcn_s_setprio(1); \
  MFMA_K(P, 0); \
  MFMA_K(P, 1); \
  __builtin_amdgcn_s_setprio(0); \
  asm volatile("s_waitcnt lgkmcnt(0)" ::: "memory"); \
} while (0)

  // ---- prologue: rec(kp=0); issue B(0)
  LOAD_REC(0);
  GLDS_B(0, 0);

  // ---- main loop: 36 steps, parity-unrolled x2 (B buffer parity = s&1)
  for (int t2 = 0; t2 < 18; ++t2) {
    STEP_BODY(2 * t2, 0, 1);
    STEP_BODY(2 * t2 + 1, 1, 0);
  }

  // ---- epilogue: BN + LeakyReLU -> y (bf16, [m][512])
#pragma unroll
  for (int nf = 0; nf < 4; ++nf) {
    int o = n0 + wn * 64 + nf * 16 + (lane & 15);
    float sc = bnA[o], sh = bnB[o];
#pragma unroll
    for (int mf = 0; mf < 2; ++mf) {
#pragma unroll
      for (int j = 0; j < 4; ++j) {
        int row = wm * 32 + mf * 16 + ((lane >> 4) << 2) + j;
        float v = acc[mf][nf][j] * sc + sh;
        v = (v >= 0.f) ? v : 0.01f * v;
        y[(size_t)(m0 + row) * 512 + o] = f2bu(v);
      }
    }
  }
#undef GLDS_B
#undef LOAD_REC
#undef WRITE_A
#undef MFMA_K
#undef STEP_BODY
}

// ---------------- Kernel 5: final 1x1 convs (K=512 block-diagonal, N=69) + scatter
__global__ __launch_bounds__(256) void k_final(const unsigned short* __restrict__ y,
    const unsigned short* __restrict__ W2t, const float* __restrict__ bias2,
    float* __restrict__ out) {
  __shared__ unsigned short As[64 * 40];
  __shared__ unsigned short Bs[80 * 40];
  int tid  = threadIdx.x;
  int lane = tid & 63;
  int wid  = tid >> 6;
  int m0   = blockIdx.x * 64;
  f32x4 acc[5] = {};
  for (int ksv = 0; ksv < 16; ++ksv) {
    __syncthreads();
    {
      int px = tid >> 2;
      int ch = (tid & 3) << 3;
      u16x8 v = *reinterpret_cast<const u16x8*>(y + (size_t)(m0 + px) * 512 + ksv * 32 + ch);
      *reinterpret_cast<u16x8*>(&As[px * 40 + ch]) = v;
    }
    {
      int j = tid >> 2, ch = (tid & 3) << 3;
      u16x8 v = *reinterpret_cast<const u16x8*>(W2t + (size_t)j * 512 + ksv * 32 + ch);
      *reinterpret_cast<u16x8*>(&Bs[j * 40 + ch]) = v;
      if (tid < 64) {
        int un = 256 + tid;
        int j2 = un >> 2, c2 = (un & 3) << 3;
        u16x8 v2 = *reinterpret_cast<const u16x8*>(W2t + (size_t)j2 * 512 + ksv * 32 + c2);
        *reinterpret_cast<u16x8*>(&Bs[j2 * 40 + c2]) = v2;
      }
    }
    __syncthreads();
    bf16x8 af = *reinterpret_cast<const bf16x8*>(&As[(wid * 16 + (lane & 15)) * 40 + ((lane >> 4) << 3)]);
#pragma unroll
    for (int nf = 0; nf < 5; ++nf) {
      bf16x8 bfr = *reinterpret_cast<const bf16x8*>(&Bs[(nf * 16 + (lane & 15)) * 40 + ((lane >> 4) << 3)]);
      acc[nf] = __builtin_amdgcn_mfma_f32_16x16x32_bf16(af, bfr, acc[nf], 0, 0, 0);
    }
  }
#pragma unroll
  for (int nf = 0; nf < 5; ++nf) {
    int j = nf * 16 + (lane & 15);
    if (j < 69) {
      float bs = bias2[j];
      int a, ch2;
      if (j < 24) { a = j >> 3; ch2 = j & 7; }
      else { int jj = j - 24; a = jj / 15; ch2 = 10 + (jj % 15); }
#pragma unroll
      for (int q = 0; q < 4; ++q) {
        int m  = m0 + wid * 16 + ((lane >> 4) << 2) + q;
        int bb = m >> 12, hw = m & 4095;
        out[(((size_t)(bb * 3 + a)) * 25 + ch2) * 4096 + hw] = acc[nf][q] + bs;
      }
    }
  }
}

extern "C" void kernel_launch(void* const* d_in, const int* in_sizes, int n_in,
                              void* d_out, int out_size, void* d_ws, size_t ws_size,
                              hipStream_t stream) {
  const float* x      = (const float*)d_in[0];
  const float* w_conf = (const float*)d_in[1];
  const float* b_conf = (const float*)d_in[2];
  const float* w_om   = (const float*)d_in[3];
  const float* b_om   = (const float*)d_in[4];
  const float* w_dloc = (const float*)d_in[5];
  const float* g_loc  = (const float*)d_in[6];
  const float* be_loc = (const float*)d_in[7];
  const float* m_loc  = (const float*)d_in[8];
  const float* v_loc  = (const float*)d_in[9];
  const float* w_locx = (const float*)d_in[10];
  const float* b_locx = (const float*)d_in[11];
  const float* w_dcla = (const float*)d_in[12];
  const float* g_cla  = (const float*)d_in[13];
  const float* be_cla = (const float*)d_in[14];
  const float* m_cla  = (const float*)d_in[15];
  const float* v_cla  = (const float*)d_in[16];
  const float* w_clax = (const float*)d_in[17];
  const float* b_clax = (const float*)d_in[18];
  float* out = (float*)d_out;

  char* ws = (char*)d_ws;
  size_t off = 0;
  unsigned short* xTp = (unsigned short*)(ws + off); off += (size_t)8 * HP * HP * C_ * 2;
  unsigned short* wT  = (unsigned short*)(ws + off); off += (size_t)512 * K_ * 2;
  unsigned short* W2t = (unsigned short*)(ws + off); off += (size_t)80 * 512 * 2;
  unsigned short* wB  = (unsigned short*)(ws + off); off += (size_t)48 * 256 * 2;
  float* bnA   = (float*)(ws + off); off += 512 * 4;
  float* bnB   = (float*)(ws + off); off += 512 * 4;
  float* bias2 = (float*)(ws + off); off += 128 * 4;
  unsigned int* rec_i = (unsigned int*)(ws + off); off += (size_t)294912 * 4;
  float4* rec_w       = (float4*)(ws + off);       off += (size_t)294912 * 16;
  unsigned short* y   = (unsigned short*)(ws + off); off += (size_t)32768 * 512 * 2;

  k_transpose<<<2048, 256, 0, stream>>>(x, xTp);
  {
    int total = 512 * K_ + 80 * 512 + 48 * 256 + 512 + 80;
    k_prep<<<(total + 255) / 256, 256, 0, stream>>>(w_dloc, w_dcla, w_locx, w_clax,
        g_loc, be_loc, m_loc, v_loc, g_cla, be_cla, m_cla, v_cla, b_locx, b_clax,
        w_om, w_conf, wT, W2t, wB, bnA, bnB, bias2);
  }
  k_offsets<<<256, 256, 0, stream>>>(xTp, wB, b_om, b_conf, rec_i, rec_w, out);
  k_deform_gemm<<<2048, 256, 0, stream>>>(xTp, wT, rec_i, rec_w, bnA, bnB, y);
  k_final<<<512, 256, 0, stream>>>(y, W2t, bias2, out);
}

// Round 8
// 203.398 us; speedup vs baseline: 1.3884x; 1.0301x over previous
//
#include <hip/hip_runtime.h>
#include <hip/hip_bf16.h>
#include <math.h>

using u16x8  = __attribute__((ext_vector_type(8))) unsigned short;
using bf16x8 = __attribute__((ext_vector_type(8))) __bf16;
using f32x4  = __attribute__((ext_vector_type(4))) float;

#define HP 66
#define C_ 256
#define K_ 2304

static __device__ __forceinline__ float bu2f(unsigned short u) {
  unsigned int v = ((unsigned int)u) << 16;
  return __builtin_bit_cast(float, v);
}
static __device__ __forceinline__ unsigned short f2bu(float f) {
  return __builtin_bit_cast(unsigned short, (__bf16)f);
}
static __device__ __forceinline__ void glds16(const unsigned short* g, unsigned short* l) {
  __builtin_amdgcn_global_load_lds((const __attribute__((address_space(1))) void*)g,
                                   (__attribute__((address_space(3))) void*)l, 16, 0, 0);
}

// ---------------- Kernel 1: transpose x (B,C,H,W) fp32 -> padded channels-last bf16 (B,66,66,C)
__global__ __launch_bounds__(256) void k_transpose(const float* __restrict__ x,
                                                   unsigned short* __restrict__ xTp) {
  __shared__ float tile[64][65];
  int blk = blockIdx.x;
  int b   = blk >> 8;
  int rem = blk & 255;
  int cblk = rem >> 6;
  int h    = rem & 63;
  int c0   = cblk * 64;
  int t  = threadIdx.x;
  int tw = t & 63;
  int tg = t >> 6;
  const u16x8 kz = {0, 0, 0, 0, 0, 0, 0, 0};
  const float* xb = x + (((size_t)(b * C_ + c0)) << 12) + (h << 6);
#pragma unroll
  for (int p = 0; p < 16; ++p) {
    int cl = p * 4 + tg;
    tile[cl][tw] = xb[((size_t)cl << 12) + tw];
  }
  if (t < 16) {
    int colb = (t & 8) ? 65 : 0;
    unsigned short* zp = xTp + (((size_t)(b * HP + h + 1)) * HP + colb) * C_ + c0 + ((t & 7) << 3);
    *reinterpret_cast<u16x8*>(zp) = kz;
  }
  if (h == 0) {
    for (int i = t; i < 2 * 66 * 8; i += 256) {
      int rsel = (i >= 528) ? 1 : 0;
      int j = i - rsel * 528;
      int col = j >> 3, c8 = (j & 7) << 3;
      unsigned short* zp = xTp + (((size_t)(b * HP + rsel * 65)) * HP + col) * C_ + c0 + c8;
      *reinterpret_cast<u16x8*>(zp) = kz;
    }
  }
  __syncthreads();
  unsigned short* dst = xTp + (((size_t)(b * HP + h + 1)) * HP + 1) * C_ + c0;
#pragma unroll
  for (int p = 0; p < 16; ++p) {
    int wl = p * 4 + tg;
    dst[(size_t)wl * C_ + tw] = f2bu(tile[tw][wl]);
  }
}

// ---------------- Kernel 2: weight/bn prep (wT stored pre-swizzled for LDS slot-XOR)
__global__ void k_prep(const float* __restrict__ w_dloc, const float* __restrict__ w_dcla,
                       const float* __restrict__ w_locx, const float* __restrict__ w_clax,
                       const float* __restrict__ g_loc, const float* __restrict__ be_loc,
                       const float* __restrict__ m_loc, const float* __restrict__ v_loc,
                       const float* __restrict__ g_cla, const float* __restrict__ be_cla,
                       const float* __restrict__ m_cla, const float* __restrict__ v_cla,
                       const float* __restrict__ b_locx, const float* __restrict__ b_clax,
                       const float* __restrict__ w_om, const float* __restrict__ w_conf,
                       unsigned short* __restrict__ wT, unsigned short* __restrict__ W2t,
                       unsigned short* __restrict__ wB,
                       float* __restrict__ bnA, float* __restrict__ bnB,
                       float* __restrict__ bias2) {
  int idx = blockIdx.x * blockDim.x + threadIdx.x;
  const int NWT = 512 * K_;
  const int NW2 = 80 * 512;
  const int NWB = 48 * 256;
  if (idx < NWT) {
    int o    = idx / K_;
    int rest = idx - o * K_;
    int kp   = rest >> 8;
    int cq   = rest & 255;
    int q    = cq >> 6;
    int chp  = cq & 63;
    int sp   = chp >> 3;
    int e    = chp & 7;
    int c    = (q << 6) | ((sp ^ (o & 7)) << 3) | e;   // slot-XOR pre-swizzle
    float v = (o < 256) ? w_dloc[(o * 256 + c) * 9 + kp]
                        : w_dcla[((o - 256) * 256 + c) * 9 + kp];
    wT[idx] = f2bu(v);
  } else if (idx < NWT + NW2) {
    int i2 = idx - NWT;
    int j  = i2 >> 9;
    int c2 = i2 & 511;
    float v = 0.f;
    if (j < 24) { if (c2 < 256) v = w_locx[j * 256 + c2]; }
    else if (j < 69) { if (c2 >= 256) v = w_clax[(j - 24) * 256 + (c2 - 256)]; }
    W2t[i2] = f2bu(v);
  } else if (idx < NWT + NW2 + NWB) {
    int i3 = idx - NWT - NW2;
    int j  = i3 >> 8;
    int c  = i3 & 255;
    float v = 0.f;
    if (j < 27) v = w_om[j * 256 + c];
    else if (j < 33) v = w_conf[(j - 27) * 256 + c];
    wB[i3] = f2bu(v);
  } else if (idx < NWT + NW2 + NWB + 512) {
    int o = idx - NWT - NW2 - NWB;
    float s, sh;
    if (o < 256) { s = g_loc[o] / sqrtf(v_loc[o] + 1e-5f); sh = be_loc[o] - m_loc[o] * s; }
    else { int o2 = o - 256; s = g_cla[o2] / sqrtf(v_cla[o2] + 1e-5f); sh = be_cla[o2] - m_cla[o2] * s; }
    bnA[o] = s; bnB[o] = sh;
  } else if (idx < NWT + NW2 + NWB + 512 + 80) {
    int j = idx - NWT - NW2 - NWB - 512;
    float v = 0.f;
    if (j < 24) v = b_locx[j];
    else if (j < 69) v = b_clax[j - 24];
    bias2[j] = v;
  }
}

// ---------------- Kernel 3: MFMA 1x1 conv (M=32768,N=48,K=256) -> conf + gather records
__global__ __launch_bounds__(256) void k_offsets(const unsigned short* __restrict__ xTp,
    const unsigned short* __restrict__ wB,
    const float* __restrict__ b_om, const float* __restrict__ b_conf,
    unsigned int* __restrict__ rec_i, float4* __restrict__ rec_w,
    float* __restrict__ out) {
  __shared__ unsigned short As[128 * 40];
  __shared__ unsigned short Bs[48 * 40];
  __shared__ float P[128 * 49];
  const int tid  = threadIdx.x;
  const int lane = tid & 63;
  const int wv   = tid >> 6;
  const int m0   = blockIdx.x * 128;
  const int b    = m0 >> 12;
  f32x4 acc[2][3] = {};
  for (int ks = 0; ks < 8; ++ks) {
#pragma unroll
    for (int u = 0; u < 2; ++u) {
      int un = u * 256 + tid;
      int px = un >> 2;
      int c8 = (un & 3) << 3;
      int m  = m0 + px;
      int h  = (m & 4095) >> 6, w = m & 63;
      const unsigned short* src = xTp + (((size_t)(b * HP + h + 1)) * HP + w + 1) * C_ + ks * 32 + c8;
      *reinterpret_cast<u16x8*>(&As[px * 40 + c8]) = *reinterpret_cast<const u16x8*>(src);
    }
    if (tid < 192) {
      int j = tid >> 2, c8 = (tid & 3) << 3;
      *reinterpret_cast<u16x8*>(&Bs[j * 40 + c8]) =
          *reinterpret_cast<const u16x8*>(&wB[j * 256 + ks * 32 + c8]);
    }
    __syncthreads();
    int kb = (lane >> 4) << 3;
    bf16x8 af[2];
#pragma unroll
    for (int mf = 0; mf < 2; ++mf)
      af[mf] = *reinterpret_cast<const bf16x8*>(&As[(wv * 32 + mf * 16 + (lane & 15)) * 40 + kb]);
#pragma unroll
    for (int nf = 0; nf < 3; ++nf) {
      bf16x8 bfr = *reinterpret_cast<const bf16x8*>(&Bs[(nf * 16 + (lane & 15)) * 40 + kb]);
#pragma unroll
      for (int mf = 0; mf < 2; ++mf)
        acc[mf][nf] = __builtin_amdgcn_mfma_f32_16x16x32_bf16(af[mf], bfr, acc[mf][nf], 0, 0, 0);
    }
    __syncthreads();
  }
#pragma unroll
  for (int mf = 0; mf < 2; ++mf)
#pragma unroll
    for (int nf = 0; nf < 3; ++nf)
#pragma unroll
      for (int jj = 0; jj < 4; ++jj)
        P[(wv * 32 + mf * 16 + ((lane >> 4) << 2) + jj) * 49 + nf * 16 + (lane & 15)] = acc[mf][nf][jj];
  __syncthreads();
  if (tid < 128) {
    int px = tid;
    int m  = m0 + px;
    int hw = m & 4095;
    int h = hw >> 6, w = hw & 63;
    const float* row = &P[px * 49];
#pragma unroll
    for (int j = 0; j < 6; ++j) {
      float v = row[27 + j] + b_conf[j];
      int a = j >> 1, ch = 8 + (j & 1);
      out[(((size_t)(b * 3 + a)) * 25 + ch) * 4096 + hw] = v;
    }
#pragma unroll
    for (int k = 0; k < 9; ++k) {
      float o1 = row[k] + b_om[k];
      float o2 = row[9 + k] + b_om[9 + k];
      float mz = row[18 + k] + b_om[18 + k];
      float mk = 1.f / (1.f + __expf(-mz));
      float pr = (float)(h + k / 3) + o1;
      float pc = (float)(w + k % 3) + o2;
      pr = fminf(fmaxf(pr, 0.f), 65.f);
      pc = fminf(fmaxf(pc, 0.f), 65.f);
      int r0 = (int)floorf(pr);
      int c0 = (int)floorf(pc);
      int r1 = min(r0 + 1, 65);
      int c1 = min(c0 + 1, 65);
      float ar = 1.f + (float)r0 - pr;
      float br = 1.f - ((float)r1 - pr);
      float ac = 1.f + (float)c0 - pc;
      float bc = 1.f - ((float)c1 - pc);
      int ridx = m * 9 + k;
      rec_i[ridx] = (unsigned)r0 | ((unsigned)c0 << 8) | ((unsigned)r1 << 16) | ((unsigned)c1 << 24);
      rec_w[ridx] = make_float4(ar * ac * mk, br * bc * mk, ar * bc * mk, br * ac * mk);
    }
  }
}

// ---------------- Kernel 4: fused gather + dual deform-conv GEMM
// 4-wave blocks, tile 64x128, acc[2][4]=32 AGPR, 40 KB LDS.
// Depth-1 tap/rec prefetch with static counted vmcnt; one tap reg set (WAR reuse).
__global__ __launch_bounds__(256, 3) void k_deform_gemm(
    const unsigned short* __restrict__ xTp, const unsigned short* __restrict__ wT,
    const unsigned int* __restrict__ rec_i, const float4* __restrict__ rec_w,
    const float* __restrict__ bnA, const float* __restrict__ bnB,
    unsigned short* __restrict__ y) {
  __shared__ unsigned short Asl[64 * 64];       // 8 KB
  __shared__ unsigned short Bsl[2][128 * 64];   // 32 KB
  const int tid   = threadIdx.x;
  const int bid   = blockIdx.x;
  const int img   = bid & 7;           // image per XCD
  const int inner = bid >> 3;          // 0..255
  const int mrow  = inner >> 2;        // 0..63
  const int n0    = (inner & 3) << 7;  // 0,128,256,384
  const int m0    = (img << 12) + (mrow << 6);
  const int lane  = tid & 63;
  const int wid   = tid >> 6;          // 0..3
  const int wm    = wid >> 1;          // 0..1
  const int wn    = wid & 1;           // 0..1
  f32x4 acc[2][4] = {};
  const unsigned short* xb = xTp + (size_t)img * (HP * HP * C_);

  const int pxq = tid >> 3;                        // 0..31
  const int chx = (((tid & 7) ^ (pxq & 7)) << 3);  // pre-swizzled global chunk
  const int rb0 = (m0 + pxq) * 9;
  const int rb1 = (m0 + 32 + pxq) * 9;
  const unsigned short* wrow = wT + (size_t)(n0 + wid * 32 + (lane >> 3)) * K_ + (lane & 7) * 8;

  unsigned int ri_n0, ri_n1;
  float4 rw_n0, rw_n1;
  float4 rw0, rw1;
  int offc0[4], offc1[4];
  u16x8 tap[8];   // [0..3]=px0 taps, [4..7]=px1 taps — static indices only

#define DECODE(RI0, RI1, RW0, RW1) do { \
  rw0 = (RW0); rw1 = (RW1); \
  { unsigned int ri = (RI0); \
    int r0 = ri & 255, c0v = (ri >> 8) & 255, r1 = (ri >> 16) & 255, c1v = ri >> 24; \
    offc0[0] = (r0 * 66 + c0v) << 8; offc0[1] = (r1 * 66 + c1v) << 8; \
    offc0[2] = (r0 * 66 + c1v) << 8; offc0[3] = (r1 * 66 + c0v) << 8; } \
  { unsigned int ri = (RI1); \
    int r0 = ri & 255, c0v = (ri >> 8) & 255, r1 = (ri >> 16) & 255, c1v = ri >> 24; \
    offc1[0] = (r0 * 66 + c0v) << 8; offc1[1] = (r1 * 66 + c1v) << 8; \
    offc1[2] = (r0 * 66 + c1v) << 8; offc1[3] = (r1 * 66 + c0v) << 8; } \
} while (0)

#define REC_ISSUE(KP) do { \
  ri_n0 = rec_i[rb0 + (KP)]; ri_n1 = rec_i[rb1 + (KP)]; \
  rw_n0 = rec_w[rb0 + (KP)]; rw_n1 = rec_w[rb1 + (KP)]; \
} while (0)

#define TAPS_ISSUE(COL) do { \
  const unsigned short* bq_ = xb + ((COL) << 6) + chx; \
  tap[0] = *reinterpret_cast<const u16x8*>(bq_ + offc0[0]); \
  tap[1] = *reinterpret_cast<const u16x8*>(bq_ + offc0[1]); \
  tap[2] = *reinterpret_cast<const u16x8*>(bq_ + offc0[2]); \
  tap[3] = *reinterpret_cast<const u16x8*>(bq_ + offc0[3]); \
  tap[4] = *reinterpret_cast<const u16x8*>(bq_ + offc1[0]); \
  tap[5] = *reinterpret_cast<const u16x8*>(bq_ + offc1[1]); \
  tap[6] = *reinterpret_cast<const u16x8*>(bq_ + offc1[2]); \
  tap[7] = *reinterpret_cast<const u16x8*>(bq_ + offc1[3]); \
} while (0)

#define LERP() do { \
  u16x8 o0, o1; \
  _Pragma("unroll") \
  for (int j = 0; j < 8; ++j) { \
    float v = rw0.x * bu2f(tap[0][j]) + rw0.y * bu2f(tap[1][j]) \
            + rw0.z * bu2f(tap[2][j]) + rw0.w * bu2f(tap[3][j]); \
    o0[j] = f2bu(v); \
  } \
  *reinterpret_cast<u16x8*>(&Asl[pxq * 64 + ((tid & 7) << 3)]) = o0; \
  _Pragma("unroll") \
  for (int j = 0; j < 8; ++j) { \
    float v = rw1.x * bu2f(tap[4][j]) + rw1.y * bu2f(tap[5][j]) \
            + rw1.z * bu2f(tap[6][j]) + rw1.w * bu2f(tap[7][j]); \
    o1[j] = f2bu(v); \
  } \
  *reinterpret_cast<u16x8*>(&Asl[(32 + pxq) * 64 + ((tid & 7) << 3)]) = o1; \
} while (0)

#define GLDS_B(NP, SS) do { \
  _Pragma("unroll") \
  for (int i = 0; i < 4; ++i) \
    glds16(wrow + (size_t)(SS) * 64 + (size_t)i * 8 * K_, \
           (unsigned short*)&Bsl[NP][(wid * 32 + i * 8) * 64]); \
} while (0)

#define MFMA_K(P, ksub) do { \
  const int sl = (ksub) * 4 + (lane >> 4); \
  const int ps = (sl ^ (lane & 7)) << 3; \
  bf16x8 af[2]; \
  _Pragma("unroll") \
  for (int mf = 0; mf < 2; ++mf) \
    af[mf] = *reinterpret_cast<const bf16x8*>(&Asl[(wm * 32 + mf * 16 + (lane & 15)) * 64 + ps]); \
  _Pragma("unroll") \
  for (int nf = 0; nf < 4; ++nf) { \
    bf16x8 bfr = *reinterpret_cast<const bf16x8*>(&Bsl[P][(wn * 64 + nf * 16 + (lane & 15)) * 64 + ps]); \
    _Pragma("unroll") \
    for (int mf = 0; mf < 2; ++mf) \
      acc[mf][nf] = __builtin_amdgcn_mfma_f32_16x16x32_bf16(af[mf], bfr, acc[mf][nf], 0, 0, 0); \
  } \
} while (0)

// Steady-state step: S = 4*t4 + Q, t4 in [0,8), Q literal 0..3.
// Top: wait taps(S)/rec (leave B(S)=4 in flight). Issue next-step loads. Pre-MFMA:
// wait B(S) (leave taps(S+1)+B(S+1)[+rec] = 12|16).
#define STEP_STEADY(Q) do { \
  __builtin_amdgcn_s_barrier(); \
  __builtin_amdgcn_sched_barrier(0); \
  asm volatile("s_waitcnt vmcnt(4)" ::: "memory"); \
  __builtin_amdgcn_sched_barrier(0); \
  LERP(); \
  if ((Q) == 3) DECODE(ri_n0, ri_n1, rw_n0, rw_n1); \
  if ((Q) == 2) REC_ISSUE(t4 + 1); \
  TAPS_ISSUE(((Q) + 1) & 3); \
  GLDS_B(((Q) + 1) & 1, 4 * t4 + (Q) + 1); \
  __builtin_amdgcn_sched_barrier(0); \
  if ((Q) == 2) asm volatile("s_waitcnt vmcnt(16) lgkmcnt(0)" ::: "memory"); \
  else          asm volatile("s_waitcnt vmcnt(12) lgkmcnt(0)" ::: "memory"); \
  __builtin_amdgcn_sched_barrier(0); \
  __builtin_amdgcn_s_barrier(); \
  __builtin_amdgcn_sched_barrier(0); \
  __builtin_amdgcn_s_setprio(1); \
  MFMA_K((Q) & 1, 0); \
  MFMA_K((Q) & 1, 1); \
  __builtin_amdgcn_s_setprio(0); \
} while (0)

  // ---- prologue: rec(kp=0) sync -> decode; issue taps(0); issue B(0)
  {
    unsigned int ri0 = rec_i[rb0];
    unsigned int ri1 = rec_i[rb1];
    float4 w0 = rec_w[rb0];
    float4 w1 = rec_w[rb1];
    DECODE(ri0, ri1, w0, w1);
  }
  TAPS_ISSUE(0);
  GLDS_B(0, 0);

  // ---- steady loop: steps 0..31
  for (int t4 = 0; t4 < 8; ++t4) {
    STEP_STEADY(0);
    STEP_STEADY(1);
    STEP_STEADY(2);
    STEP_STEADY(3);
  }

  // ---- tail: steps 32..35 (kp=8, no further rec)
  // S=32 (P=0)
  __builtin_amdgcn_s_barrier();
  __builtin_amdgcn_sched_barrier(0);
  asm volatile("s_waitcnt vmcnt(4)" ::: "memory");
  __builtin_amdgcn_sched_barrier(0);
  LERP();
  TAPS_ISSUE(1); GLDS_B(1, 33);
  __builtin_amdgcn_sched_barrier(0);
  asm volatile("s_waitcnt vmcnt(12) lgkmcnt(0)" ::: "memory");
  __builtin_amdgcn_sched_barrier(0);
  __builtin_amdgcn_s_barrier();
  __builtin_amdgcn_sched_barrier(0);
  __builtin_amdgcn_s_setprio(1); MFMA_K(0, 0); MFMA_K(0, 1); __builtin_amdgcn_s_setprio(0);
  // S=33 (P=1)
  __builtin_amdgcn_s_barrier();
  __builtin_amdgcn_sched_barrier(0);
  asm volatile("s_waitcnt vmcnt(4)" ::: "memory");
  __builtin_amdgcn_sched_barrier(0);
  LERP();
  TAPS_ISSUE(2); GLDS_B(0, 34);
  __builtin_amdgcn_sched_barrier(0);
  asm volatile("s_waitcnt vmcnt(12) lgkmcnt(0)" ::: "memory");
  __builtin_amdgcn_sched_barrier(0);
  __builtin_amdgcn_s_barrier();
  __builtin_amdgcn_sched_barrier(0);
  __builtin_amdgcn_s_setprio(1); MFMA_K(1, 0); MFMA_K(1, 1); __builtin_amdgcn_s_setprio(0);
  // S=34 (P=0)
  __builtin_amdgcn_s_barrier();
  __builtin_amdgcn_sched_barrier(0);
  asm volatile("s_waitcnt vmcnt(4)" ::: "memory");
  __builtin_amdgcn_sched_barrier(0);
  LERP();
  TAPS_ISSUE(3); GLDS_B(1, 35);
  __builtin_amdgcn_sched_barrier(0);
  asm volatile("s_waitcnt vmcnt(12) lgkmcnt(0)" ::: "memory");
  __builtin_amdgcn_sched_barrier(0);
  __builtin_amdgcn_s_barrier();
  __builtin_amdgcn_sched_barrier(0);
  __builtin_amdgcn_s_setprio(1); MFMA_K(0, 0); MFMA_K(0, 1); __builtin_amdgcn_s_setprio(0);
  // S=35 (P=1)
  __builtin_amdgcn_s_barrier();
  __builtin_amdgcn_sched_barrier(0);
  asm volatile("s_waitcnt vmcnt(4)" ::: "memory");
  __builtin_amdgcn_sched_barrier(0);
  LERP();
  __builtin_amdgcn_sched_barrier(0);
  asm volatile("s_waitcnt vmcnt(0) lgkmcnt(0)" ::: "memory");
  __builtin_amdgcn_sched_barrier(0);
  __builtin_amdgcn_s_barrier();
  __builtin_amdgcn_sched_barrier(0);
  __builtin_amdgcn_s_setprio(1); MFMA_K(1, 0); MFMA_K(1, 1); __builtin_amdgcn_s_setprio(0);

  // ---- epilogue: BN + LeakyReLU -> y (bf16, [m][512])
#pragma unroll
  for (int nf = 0; nf < 4; ++nf) {
    int o = n0 + wn * 64 + nf * 16 + (lane & 15);
    float sc = bnA[o], sh = bnB[o];
#pragma unroll
    for (int mf = 0; mf < 2; ++mf) {
#pragma unroll
      for (int j = 0; j < 4; ++j) {
        int row = wm * 32 + mf * 16 + ((lane >> 4) << 2) + j;
        float v = acc[mf][nf][j] * sc + sh;
        v = (v >= 0.f) ? v : 0.01f * v;
        y[(size_t)(m0 + row) * 512 + o] = f2bu(v);
      }
    }
  }
#undef DECODE
#undef REC_ISSUE
#undef TAPS_ISSUE
#undef LERP
#undef GLDS_B
#undef MFMA_K
#undef STEP_STEADY
}

// ---------------- Kernel 5: final 1x1 convs (K=512 block-diagonal, N=69) + scatter
__global__ __launch_bounds__(256) void k_final(const unsigned short* __restrict__ y,
    const unsigned short* __restrict__ W2t, const float* __restrict__ bias2,
    float* __restrict__ out) {
  __shared__ unsigned short As[64 * 40];
  __shared__ unsigned short Bs[80 * 40];
  int tid  = threadIdx.x;
  int lane = tid & 63;
  int wid  = tid >> 6;
  int m0   = blockIdx.x * 64;
  f32x4 acc[5] = {};
  for (int ksv = 0; ksv < 16; ++ksv) {
    __syncthreads();
    {
      int px = tid >> 2;
      int ch = (tid & 3) << 3;
      u16x8 v = *reinterpret_cast<const u16x8*>(y + (size_t)(m0 + px) * 512 + ksv * 32 + ch);
      *reinterpret_cast<u16x8*>(&As[px * 40 + ch]) = v;
    }
    {
      int j = tid >> 2, ch = (tid & 3) << 3;
      u16x8 v = *reinterpret_cast<const u16x8*>(W2t + (size_t)j * 512 + ksv * 32 + ch);
      *reinterpret_cast<u16x8*>(&Bs[j * 40 + ch]) = v;
      if (tid < 64) {
        int un = 256 + tid;
        int j2 = un >> 2, c2 = (un & 3) << 3;
        u16x8 v2 = *reinterpret_cast<const u16x8*>(W2t + (size_t)j2 * 512 + ksv * 32 + c2);
        *reinterpret_cast<u16x8*>(&Bs[j2 * 40 + c2]) = v2;
      }
    }
    __syncthreads();
    bf16x8 af = *reinterpret_cast<const bf16x8*>(&As[(wid * 16 + (lane & 15)) * 40 + ((lane >> 4) << 3)]);
#pragma unroll
    for (int nf = 0; nf < 5; ++nf) {
      bf16x8 bfr = *reinterpret_cast<const bf16x8*>(&Bs[(nf * 16 + (lane & 15)) * 40 + ((lane >> 4) << 3)]);
      acc[nf] = __builtin_amdgcn_mfma_f32_16x16x32_bf16(af, bfr, acc[nf], 0, 0, 0);
    }
  }
#pragma unroll
  for (int nf = 0; nf < 5; ++nf) {
    int j = nf * 16 + (lane & 15);
    if (j < 69) {
      float bs = bias2[j];
      int a, ch2;
      if (j < 24) { a = j >> 3; ch2 = j & 7; }
      else { int jj = j - 24; a = jj / 15; ch2 = 10 + (jj % 15); }
#pragma unroll
      for (int q = 0; q < 4; ++q) {
        int m  = m0 + wid * 16 + ((lane >> 4) << 2) + q;
        int bb = m >> 12, hw = m & 4095;
        out[(((size_t)(bb * 3 + a)) * 25 + ch2) * 4096 + hw] = acc[nf][q] + bs;
      }
    }
  }
}

extern "C" void kernel_launch(void* const* d_in, const int* in_sizes, int n_in,
                              void* d_out, int out_size, void* d_ws, size_t ws_size,
                              hipStream_t stream) {
  const float* x      = (const float*)d_in[0];
  const float* w_conf = (const float*)d_in[1];
  const float* b_conf = (const float*)d_in[2];
  const float* w_om   = (const float*)d_in[3];
  const float* b_om   = (const float*)d_in[4];
  const float* w_dloc = (const float*)d_in[5];
  const float* g_loc  = (const float*)d_in[6];
  const float* be_loc = (const float*)d_in[7];
  const float* m_loc  = (const float*)d_in[8];
  const float* v_loc  = (const float*)d_in[9];
  const float* w_locx = (const float*)d_in[10];
  const float* b_locx = (const float*)d_in[11];
  const float* w_dcla = (const float*)d_in[12];
  const float* g_cla  = (const float*)d_in[13];
  const float* be_cla = (const float*)d_in[14];
  const float* m_cla  = (const float*)d_in[15];
  const float* v_cla  = (const float*)d_in[16];
  const float* w_clax = (const float*)d_in[17];
  const float* b_clax = (const float*)d_in[18];
  float* out = (float*)d_out;

  char* ws = (char*)d_ws;
  size_t off = 0;
  unsigned short* xTp = (unsigned short*)(ws + off); off += (size_t)8 * HP * HP * C_ * 2;
  unsigned short* wT  = (unsigned short*)(ws + off); off += (size_t)512 * K_ * 2;
  unsigned short* W2t = (unsigned short*)(ws + off); off += (size_t)80 * 512 * 2;
  unsigned short* wB  = (unsigned short*)(ws + off); off += (size_t)48 * 256 * 2;
  float* bnA   = (float*)(ws + off); off += 512 * 4;
  float* bnB   = (float*)(ws + off); off += 512 * 4;
  float* bias2 = (float*)(ws + off); off += 128 * 4;
  unsigned int* rec_i = (unsigned int*)(ws + off); off += (size_t)294912 * 4;
  float4* rec_w       = (float4*)(ws + off);       off += (size_t)294912 * 16;
  unsigned short* y   = (unsigned short*)(ws + off); off += (size_t)32768 * 512 * 2;

  k_transpose<<<2048, 256, 0, stream>>>(x, xTp);
  {
    int total = 512 * K_ + 80 * 512 + 48 * 256 + 512 + 80;
    k_prep<<<(total + 255) / 256, 256, 0, stream>>>(w_dloc, w_dcla, w_locx, w_clax,
        g_loc, be_loc, m_loc, v_loc, g_cla, be_cla, m_cla, v_cla, b_locx, b_clax,
        w_om, w_conf, wT, W2t, wB, bnA, bnB, bias2);
  }
  k_offsets<<<256, 256, 0, stream>>>(xTp, wB, b_om, b_conf, rec_i, rec_w, out);
  k_deform_gemm<<<2048, 256, 0, stream>>>(xTp, wT, rec_i, rec_w, bnA, bnB, y);
  k_final<<<512, 256, 0, stream>>>(y, W2t, bias2, out);
}

// Round 11
// 168.093 us; speedup vs baseline: 1.6801x; 1.2100x over previous
//
#include <hip/hip_runtime.h>
#include <hip/hip_bf16.h>
#include <math.h>

using u16x8  = __attribute__((ext_vector_type(8))) unsigned short;
using bf16x8 = __attribute__((ext_vector_type(8))) __bf16;
using f32x4  = __attribute__((ext_vector_type(4))) float;

#define HP 66
#define C_ 256
#define K_ 2304

static __device__ __forceinline__ float bu2f(unsigned short u) {
  unsigned int v = ((unsigned int)u) << 16;
  return __builtin_bit_cast(float, v);
}
static __device__ __forceinline__ unsigned short f2bu(float f) {
  return __builtin_bit_cast(unsigned short, (__bf16)f);
}
static __device__ __forceinline__ void glds16(const unsigned short* g, unsigned short* l) {
  __builtin_amdgcn_global_load_lds((const __attribute__((address_space(1))) void*)g,
                                   (__attribute__((address_space(3))) void*)l, 16, 0, 0);
}

// ---------------- Kernel 1: transpose x (B,C,H,W) fp32 -> padded channels-last bf16 (B,66,66,C)
__global__ __launch_bounds__(256) void k_transpose(const float* __restrict__ x,
                                                   unsigned short* __restrict__ xTp) {
  __shared__ float tile[64][65];
  int blk = blockIdx.x;
  int b   = blk >> 8;
  int rem = blk & 255;
  int cblk = rem >> 6;
  int h    = rem & 63;
  int c0   = cblk * 64;
  int t  = threadIdx.x;
  int tw = t & 63;
  int tg = t >> 6;
  const u16x8 kz = {0, 0, 0, 0, 0, 0, 0, 0};
  const float* xb = x + (((size_t)(b * C_ + c0)) << 12) + (h << 6);
#pragma unroll
  for (int p = 0; p < 16; ++p) {
    int cl = p * 4 + tg;
    tile[cl][tw] = xb[((size_t)cl << 12) + tw];
  }
  if (t < 16) {
    int colb = (t & 8) ? 65 : 0;
    unsigned short* zp = xTp + (((size_t)(b * HP + h + 1)) * HP + colb) * C_ + c0 + ((t & 7) << 3);
    *reinterpret_cast<u16x8*>(zp) = kz;
  }
  if (h == 0) {
    for (int i = t; i < 2 * 66 * 8; i += 256) {
      int rsel = (i >= 528) ? 1 : 0;
      int j = i - rsel * 528;
      int col = j >> 3, c8 = (j & 7) << 3;
      unsigned short* zp = xTp + (((size_t)(b * HP + rsel * 65)) * HP + col) * C_ + c0 + c8;
      *reinterpret_cast<u16x8*>(zp) = kz;
    }
  }
  __syncthreads();
  unsigned short* dst = xTp + (((size_t)(b * HP + h + 1)) * HP + 1) * C_ + c0;
#pragma unroll
  for (int p = 0; p < 16; ++p) {
    int wl = p * 4 + tg;
    dst[(size_t)wl * C_ + tw] = f2bu(tile[tw][wl]);
  }
}

// ---------------- Kernel 2: weight/bn prep (wT stored pre-swizzled for LDS slot-XOR)
__global__ void k_prep(const float* __restrict__ w_dloc, const float* __restrict__ w_dcla,
                       const float* __restrict__ w_locx, const float* __restrict__ w_clax,
                       const float* __restrict__ g_loc, const float* __restrict__ be_loc,
                       const float* __restrict__ m_loc, const float* __restrict__ v_loc,
                       const float* __restrict__ g_cla, const float* __restrict__ be_cla,
                       const float* __restrict__ m_cla, const float* __restrict__ v_cla,
                       const float* __restrict__ b_locx, const float* __restrict__ b_clax,
                       const float* __restrict__ w_om, const float* __restrict__ w_conf,
                       unsigned short* __restrict__ wT, unsigned short* __restrict__ W2t,
                       unsigned short* __restrict__ wB,
                       float* __restrict__ bnA, float* __restrict__ bnB,
                       float* __restrict__ bias2) {
  int idx = blockIdx.x * blockDim.x + threadIdx.x;
  const int NWT = 512 * K_;
  const int NW2 = 80 * 512;
  const int NWB = 48 * 256;
  if (idx < NWT) {
    int o    = idx / K_;
    int rest = idx - o * K_;
    int kp   = rest >> 8;
    int cq   = rest & 255;
    int q    = cq >> 6;
    int chp  = cq & 63;
    int sp   = chp >> 3;
    int e    = chp & 7;
    int c    = (q << 6) | ((sp ^ (o & 7)) << 3) | e;   // slot-XOR pre-swizzle
    float v = (o < 256) ? w_dloc[(o * 256 + c) * 9 + kp]
                        : w_dcla[((o - 256) * 256 + c) * 9 + kp];
    wT[idx] = f2bu(v);
  } else if (idx < NWT + NW2) {
    int i2 = idx - NWT;
    int j  = i2 >> 9;
    int c2 = i2 & 511;
    float v = 0.f;
    if (j < 24) { if (c2 < 256) v = w_locx[j * 256 + c2]; }
    else if (j < 69) { if (c2 >= 256) v = w_clax[(j - 24) * 256 + (c2 - 256)]; }
    W2t[i2] = f2bu(v);
  } else if (idx < NWT + NW2 + NWB) {
    int i3 = idx - NWT - NW2;
    int j  = i3 >> 8;
    int c  = i3 & 255;
    float v = 0.f;
    if (j < 27) v = w_om[j * 256 + c];
    else if (j < 33) v = w_conf[(j - 27) * 256 + c];
    wB[i3] = f2bu(v);
  } else if (idx < NWT + NW2 + NWB + 512) {
    int o = idx - NWT - NW2 - NWB;
    float s, sh;
    if (o < 256) { s = g_loc[o] / sqrtf(v_loc[o] + 1e-5f); sh = be_loc[o] - m_loc[o] * s; }
    else { int o2 = o - 256; s = g_cla[o2] / sqrtf(v_cla[o2] + 1e-5f); sh = be_cla[o2] - m_cla[o2] * s; }
    bnA[o] = s; bnB[o] = sh;
  } else if (idx < NWT + NW2 + NWB + 512 + 80) {
    int j = idx - NWT - NW2 - NWB - 512;
    float v = 0.f;
    if (j < 24) v = b_locx[j];
    else if (j < 69) v = b_clax[j - 24];
    bias2[j] = v;
  }
}

// ---------------- Kernel 3: MFMA 1x1 conv (M=32768,N=48,K=256) -> conf + gather records
__global__ __launch_bounds__(256) void k_offsets(const unsigned short* __restrict__ xTp,
    const unsigned short* __restrict__ wB,
    const float* __restrict__ b_om, const float* __restrict__ b_conf,
    unsigned int* __restrict__ rec_i, float4* __restrict__ rec_w,
    float* __restrict__ out) {
  __shared__ unsigned short As[128 * 40];
  __shared__ unsigned short Bs[48 * 40];
  __shared__ float P[128 * 49];
  const int tid  = threadIdx.x;
  const int lane = tid & 63;
  const int wv   = tid >> 6;
  const int m0   = blockIdx.x * 128;
  const int b    = m0 >> 12;
  f32x4 acc[2][3] = {};
  for (int ks = 0; ks < 8; ++ks) {
#pragma unroll
    for (int u = 0; u < 2; ++u) {
      int un = u * 256 + tid;
      int px = un >> 2;
      int c8 = (un & 3) << 3;
      int m  = m0 + px;
      int h  = (m & 4095) >> 6, w = m & 63;
      const unsigned short* src = xTp + (((size_t)(b * HP + h + 1)) * HP + w + 1) * C_ + ks * 32 + c8;
      *reinterpret_cast<u16x8*>(&As[px * 40 + c8]) = *reinterpret_cast<const u16x8*>(src);
    }
    if (tid < 192) {
      int j = tid >> 2, c8 = (tid & 3) << 3;
      *reinterpret_cast<u16x8*>(&Bs[j * 40 + c8]) =
          *reinterpret_cast<const u16x8*>(&wB[j * 256 + ks * 32 + c8]);
    }
    __syncthreads();
    int kb = (lane >> 4) << 3;
    bf16x8 af[2];
#pragma unroll
    for (int mf = 0; mf < 2; ++mf)
      af[mf] = *reinterpret_cast<const bf16x8*>(&As[(wv * 32 + mf * 16 + (lane & 15)) * 40 + kb]);
#pragma unroll
    for (int nf = 0; nf < 3; ++nf) {
      bf16x8 bfr = *reinterpret_cast<const bf16x8*>(&Bs[(nf * 16 + (lane & 15)) * 40 + kb]);
#pragma unroll
      for (int mf = 0; mf < 2; ++mf)
        acc[mf][nf] = __builtin_amdgcn_mfma_f32_16x16x32_bf16(af[mf], bfr, acc[mf][nf], 0, 0, 0);
    }
    __syncthreads();
  }
#pragma unroll
  for (int mf = 0; mf < 2; ++mf)
#pragma unroll
    for (int nf = 0; nf < 3; ++nf)
#pragma unroll
      for (int jj = 0; jj < 4; ++jj)
        P[(wv * 32 + mf * 16 + ((lane >> 4) << 2) + jj) * 49 + nf * 16 + (lane & 15)] = acc[mf][nf][jj];
  __syncthreads();
  if (tid < 128) {
    int px = tid;
    int m  = m0 + px;
    int hw = m & 4095;
    int h = hw >> 6, w = hw & 63;
    const float* row = &P[px * 49];
#pragma unroll
    for (int j = 0; j < 6; ++j) {
      float v = row[27 + j] + b_conf[j];
      int a = j >> 1, ch = 8 + (j & 1);
      out[(((size_t)(b * 3 + a)) * 25 + ch) * 4096 + hw] = v;
    }
#pragma unroll
    for (int k = 0; k < 9; ++k) {
      float o1 = row[k] + b_om[k];
      float o2 = row[9 + k] + b_om[9 + k];
      float mz = row[18 + k] + b_om[18 + k];
      float mk = 1.f / (1.f + __expf(-mz));
      float pr = (float)(h + k / 3) + o1;
      float pc = (float)(w + k % 3) + o2;
      pr = fminf(fmaxf(pr, 0.f), 65.f);
      pc = fminf(fmaxf(pc, 0.f), 65.f);
      int r0 = (int)floorf(pr);
      int c0 = (int)floorf(pc);
      int r1 = min(r0 + 1, 65);
      int c1 = min(c0 + 1, 65);
      float ar = 1.f + (float)r0 - pr;
      float br = 1.f - ((float)r1 - pr);
      float ac = 1.f + (float)c0 - pc;
      float bc = 1.f - ((float)c1 - pc);
      int ridx = m * 9 + k;
      rec_i[ridx] = (unsigned)r0 | ((unsigned)c0 << 8) | ((unsigned)r1 << 16) | ((unsigned)c1 << 24);
      rec_w[ridx] = make_float4(ar * ac * mk, br * bc * mk, ar * bc * mk, br * ac * mk);
    }
  }
}

// ---------------- Kernel 4: fused gather + dual deform-conv GEMM (bf16)
// Tile 64x256, acc[2][8], 72 KB LDS (A single 8 KB + B dbuf 2x32 KB),
// depth-1 tap/rec prefetch, counted vmcnt. bf16 path = round-8-proven numerics.
__global__ __launch_bounds__(256, 2) void k_deform_gemm(
    const unsigned short* __restrict__ xTp, const unsigned short* __restrict__ wT,
    const unsigned int* __restrict__ rec_i, const float4* __restrict__ rec_w,
    const float* __restrict__ bnA, const float* __restrict__ bnB,
    unsigned short* __restrict__ y) {
  __shared__ unsigned short Asl[64 * 64];       // 8 KB
  __shared__ unsigned short Bsl[2][256 * 64];   // 64 KB
  const int tid   = threadIdx.x;
  const int bid   = blockIdx.x;
  const int img   = bid & 7;           // image per XCD
  const int inner = bid >> 3;          // 0..127
  const int n0    = (inner & 1) << 8;  // 0 or 256
  const int mrow  = inner >> 1;        // 0..63
  const int m0    = (img << 12) + (mrow << 6);
  const int lane  = tid & 63;
  const int wid   = tid >> 6;          // 0..3
  const int wm    = wid >> 1;          // 0..1
  const int wn    = wid & 1;           // 0..1
  f32x4 acc[2][8] = {};
  const unsigned short* xb = xTp + (size_t)img * (HP * HP * C_);

  const int pxq = tid >> 3;                        // 0..31
  const int chx = (((tid & 7) ^ (pxq & 7)) << 3);  // pre-swizzled global chunk
  const int rb0 = (m0 + pxq) * 9;
  const int rb1 = (m0 + 32 + pxq) * 9;
  const unsigned short* wrow = wT + (size_t)(n0 + wid * 64 + (lane >> 3)) * K_ + (lane & 7) * 8;

  unsigned int ri_n0, ri_n1;
  float4 rw_n0, rw_n1;
  float4 rw0, rw1;
  int offc0[4], offc1[4];
  u16x8 tap[8];   // [0..3]=px0 taps, [4..7]=px1 taps — static indices only

#define DECODE(RI0, RI1, RW0, RW1) do { \
  rw0 = (RW0); rw1 = (RW1); \
  { unsigned int ri = (RI0); \
    int r0 = ri & 255, c0v = (ri >> 8) & 255, r1 = (ri >> 16) & 255, c1v = ri >> 24; \
    offc0[0] = (r0 * 66 + c0v) << 8; offc0[1] = (r1 * 66 + c1v) << 8; \
    offc0[2] = (r0 * 66 + c1v) << 8; offc0[3] = (r1 * 66 + c0v) << 8; } \
  { unsigned int ri = (RI1); \
    int r0 = ri & 255, c0v = (ri >> 8) & 255, r1 = (ri >> 16) & 255, c1v = ri >> 24; \
    offc1[0] = (r0 * 66 + c0v) << 8; offc1[1] = (r1 * 66 + c1v) << 8; \
    offc1[2] = (r0 * 66 + c1v) << 8; offc1[3] = (r1 * 66 + c0v) << 8; } \
} while (0)

#define REC_ISSUE(KP) do { \
  ri_n0 = rec_i[rb0 + (KP)]; ri_n1 = rec_i[rb1 + (KP)]; \
  rw_n0 = rec_w[rb0 + (KP)]; rw_n1 = rec_w[rb1 + (KP)]; \
} while (0)

#define TAPS_ISSUE(COL) do { \
  const unsigned short* bq_ = xb + ((COL) << 6) + chx; \
  tap[0] = *reinterpret_cast<const u16x8*>(bq_ + offc0[0]); \
  tap[1] = *reinterpret_cast<const u16x8*>(bq_ + offc0[1]); \
  tap[2] = *reinterpret_cast<const u16x8*>(bq_ + offc0[2]); \
  tap[3] = *reinterpret_cast<const u16x8*>(bq_ + offc0[3]); \
  tap[4] = *reinterpret_cast<const u16x8*>(bq_ + offc1[0]); \
  tap[5] = *reinterpret_cast<const u16x8*>(bq_ + offc1[1]); \
  tap[6] = *reinterpret_cast<const u16x8*>(bq_ + offc1[2]); \
  tap[7] = *reinterpret_cast<const u16x8*>(bq_ + offc1[3]); \
} while (0)

#define LERP() do { \
  u16x8 o0, o1; \
  _Pragma("unroll") \
  for (int j = 0; j < 8; ++j) { \
    float v = rw0.x * bu2f(tap[0][j]) + rw0.y * bu2f(tap[1][j]) \
            + rw0.z * bu2f(tap[2][j]) + rw0.w * bu2f(tap[3][j]); \
    o0[j] = f2bu(v); \
  } \
  *reinterpret_cast<u16x8*>(&Asl[pxq * 64 + ((tid & 7) << 3)]) = o0; \
  _Pragma("unroll") \
  for (int j = 0; j < 8; ++j) { \
    float v = rw1.x * bu2f(tap[4][j]) + rw1.y * bu2f(tap[5][j]) \
            + rw1.z * bu2f(tap[6][j]) + rw1.w * bu2f(tap[7][j]); \
    o1[j] = f2bu(v); \
  } \
  *reinterpret_cast<u16x8*>(&Asl[(32 + pxq) * 64 + ((tid & 7) << 3)]) = o1; \
} while (0)

#define GLDS_B(NP, SS) do { \
  _Pragma("unroll") \
  for (int i = 0; i < 8; ++i) \
    glds16(wrow + (size_t)(SS) * 64 + (size_t)i * 8 * K_, \
           (unsigned short*)&Bsl[NP][(wid * 64 + i * 8) * 64]); \
} while (0)

#define MFMA_K(P, ksub) do { \
  const int sl = (ksub) * 4 + (lane >> 4); \
  const int ps = (sl ^ (lane & 7)) << 3; \
  bf16x8 af[2]; \
  _Pragma("unroll") \
  for (int mf = 0; mf < 2; ++mf) \
    af[mf] = *reinterpret_cast<const bf16x8*>(&Asl[(wm * 32 + mf * 16 + (lane & 15)) * 64 + ps]); \
  _Pragma("unroll") \
  for (int nf = 0; nf < 8; ++nf) { \
    bf16x8 bfr = *reinterpret_cast<const bf16x8*>(&Bsl[P][(wn * 128 + nf * 16 + (lane & 15)) * 64 + ps]); \
    _Pragma("unroll") \
    for (int mf = 0; mf < 2; ++mf) \
      acc[mf][nf] = __builtin_amdgcn_mfma_f32_16x16x32_bf16(af[mf], bfr, acc[mf][nf], 0, 0, 0); \
  } \
} while (0)

// Steady step S = 4*t4 + Q. Top: wait taps(S) (keep B(S)=8). After issues:
// keep taps(S+1)8 + B(S+1)8 = 16 (+4 rec on Q2 steps, rec issued FIRST so
// Q3-top vmcnt(8) drains rec+taps, leaving only B).
#define STEP_STEADY(Q) do { \
  __builtin_amdgcn_s_barrier(); \
  __builtin_amdgcn_sched_barrier(0); \
  asm volatile("s_waitcnt vmcnt(8)" ::: "memory"); \
  __builtin_amdgcn_sched_barrier(0); \
  LERP(); \
  if ((Q) == 3) DECODE(ri_n0, ri_n1, rw_n0, rw_n1); \
  if ((Q) == 2) REC_ISSUE(t4 + 1); \
  TAPS_ISSUE(((Q) + 1) & 3); \
  GLDS_B(((Q) + 1) & 1, 4 * t4 + (Q) + 1); \
  __builtin_amdgcn_sched_barrier(0); \
  if ((Q) == 2) asm volatile("s_waitcnt vmcnt(20) lgkmcnt(0)" ::: "memory"); \
  else          asm volatile("s_waitcnt vmcnt(16) lgkmcnt(0)" ::: "memory"); \
  __builtin_amdgcn_sched_barrier(0); \
  __builtin_amdgcn_s_barrier(); \
  __builtin_amdgcn_sched_barrier(0); \
  __builtin_amdgcn_s_setprio(1); \
  MFMA_K((Q) & 1, 0); \
  MFMA_K((Q) & 1, 1); \
  __builtin_amdgcn_s_setprio(0); \
} while (0)

  // ---- prologue: rec(kp=0) sync -> decode; issue taps(0); issue B(0)
  {
    unsigned int ri0 = rec_i[rb0];
    unsigned int ri1 = rec_i[rb1];
    float4 w0 = rec_w[rb0];
    float4 w1 = rec_w[rb1];
    DECODE(ri0, ri1, w0, w1);
  }
  TAPS_ISSUE(0);
  GLDS_B(0, 0);

  // ---- steady loop: steps 0..31
  for (int t4 = 0; t4 < 8; ++t4) {
    STEP_STEADY(0);
    STEP_STEADY(1);
    STEP_STEADY(2);
    STEP_STEADY(3);
  }

  // ---- tail: steps 32..35 (kp=8)
  // S=32 (P=0)
  __builtin_amdgcn_s_barrier();
  __builtin_amdgcn_sched_barrier(0);
  asm volatile("s_waitcnt vmcnt(8)" ::: "memory");
  __builtin_amdgcn_sched_barrier(0);
  LERP();
  TAPS_ISSUE(1); GLDS_B(1, 33);
  __builtin_amdgcn_sched_barrier(0);
  asm volatile("s_waitcnt vmcnt(16) lgkmcnt(0)" ::: "memory");
  __builtin_amdgcn_sched_barrier(0);
  __builtin_amdgcn_s_barrier();
  __builtin_amdgcn_sched_barrier(0);
  __builtin_amdgcn_s_setprio(1); MFMA_K(0, 0); MFMA_K(0, 1); __builtin_amdgcn_s_setprio(0);
  // S=33 (P=1)
  __builtin_amdgcn_s_barrier();
  __builtin_amdgcn_sched_barrier(0);
  asm volatile("s_waitcnt vmcnt(8)" ::: "memory");
  __builtin_amdgcn_sched_barrier(0);
  LERP();
  TAPS_ISSUE(2); GLDS_B(0, 34);
  __builtin_amdgcn_sched_barrier(0);
  asm volatile("s_waitcnt vmcnt(16) lgkmcnt(0)" ::: "memory");
  __builtin_amdgcn_sched_barrier(0);
  __builtin_amdgcn_s_barrier();
  __builtin_amdgcn_sched_barrier(0);
  __builtin_amdgcn_s_setprio(1); MFMA_K(1, 0); MFMA_K(1, 1); __builtin_amdgcn_s_setprio(0);
  // S=34 (P=0)
  __builtin_amdgcn_s_barrier();
  __builtin_amdgcn_sched_barrier(0);
  asm volatile("s_waitcnt vmcnt(8)" ::: "memory");
  __builtin_amdgcn_sched_barrier(0);
  LERP();
  TAPS_ISSUE(3); GLDS_B(1, 35);
  __builtin_amdgcn_sched_barrier(0);
  asm volatile("s_waitcnt vmcnt(16) lgkmcnt(0)" ::: "memory");
  __builtin_amdgcn_sched_barrier(0);
  __builtin_amdgcn_s_barrier();
  __builtin_amdgcn_sched_barrier(0);
  __builtin_amdgcn_s_setprio(1); MFMA_K(0, 0); MFMA_K(0, 1); __builtin_amdgcn_s_setprio(0);
  // S=35 (P=1)
  __builtin_amdgcn_s_barrier();
  __builtin_amdgcn_sched_barrier(0);
  asm volatile("s_waitcnt vmcnt(8)" ::: "memory");
  __builtin_amdgcn_sched_barrier(0);
  LERP();
  __builtin_amdgcn_sched_barrier(0);
  asm volatile("s_waitcnt vmcnt(0) lgkmcnt(0)" ::: "memory");
  __builtin_amdgcn_sched_barrier(0);
  __builtin_amdgcn_s_barrier();
  __builtin_amdgcn_sched_barrier(0);
  __builtin_amdgcn_s_setprio(1); MFMA_K(1, 0); MFMA_K(1, 1); __builtin_amdgcn_s_setprio(0);

  // ---- epilogue: BN + LeakyReLU -> y (bf16, [m][512])
#pragma unroll
  for (int nf = 0; nf < 8; ++nf) {
    int o = n0 + wn * 128 + nf * 16 + (lane & 15);
    float sc = bnA[o], sh = bnB[o];
#pragma unroll
    for (int mf = 0; mf < 2; ++mf) {
#pragma unroll
      for (int j = 0; j < 4; ++j) {
        int row = wm * 32 + mf * 16 + ((lane >> 4) << 2) + j;
        float v = acc[mf][nf][j] * sc + sh;
        v = (v >= 0.f) ? v : 0.01f * v;
        y[(size_t)(m0 + row) * 512 + o] = f2bu(v);
      }
    }
  }
#undef DECODE
#undef REC_ISSUE
#undef TAPS_ISSUE
#undef LERP
#undef GLDS_B
#undef MFMA_K
#undef STEP_STEADY
}

// ---------------- Kernel 5: final 1x1 convs (K=512 block-diagonal, N=69) + scatter
__global__ __launch_bounds__(256) void k_final(const unsigned short* __restrict__ y,
    const unsigned short* __restrict__ W2t, const float* __restrict__ bias2,
    float* __restrict__ out) {
  __shared__ unsigned short As[64 * 40];
  __shared__ unsigned short Bs[80 * 40];
  int tid  = threadIdx.x;
  int lane = tid & 63;
  int wid  = tid >> 6;
  int m0   = blockIdx.x * 64;
  f32x4 acc[5] = {};
  for (int ksv = 0; ksv < 16; ++ksv) {
    __syncthreads();
    {
      int px = tid >> 2;
      int ch = (tid & 3) << 3;
      u16x8 v = *reinterpret_cast<const u16x8*>(y + (size_t)(m0 + px) * 512 + ksv * 32 + ch);
      *reinterpret_cast<u16x8*>(&As[px * 40 + ch]) = v;
    }
    {
      int j = tid >> 2, ch = (tid & 3) << 3;
      u16x8 v = *reinterpret_cast<const u16x8*>(W2t + (size_t)j * 512 + ksv * 32 + ch);
      *reinterpret_cast<u16x8*>(&Bs[j * 40 + ch]) = v;
      if (tid < 64) {
        int un = 256 + tid;
        int j2 = un >> 2, c2 = (un & 3) << 3;
        u16x8 v2 = *reinterpret_cast<const u16x8*>(W2t + (size_t)j2 * 512 + ksv * 32 + c2);
        *reinterpret_cast<u16x8*>(&Bs[j2 * 40 + c2]) = v2;
      }
    }
    __syncthreads();
    bf16x8 af = *reinterpret_cast<const bf16x8*>(&As[(wid * 16 + (lane & 15)) * 40 + ((lane >> 4) << 3)]);
#pragma unroll
    for (int nf = 0; nf < 5; ++nf) {
      bf16x8 bfr = *reinterpret_cast<const bf16x8*>(&Bs[(nf * 16 + (lane & 15)) * 40 + ((lane >> 4) << 3)]);
      acc[nf] = __builtin_amdgcn_mfma_f32_16x16x32_bf16(af, bfr, acc[nf], 0, 0, 0);
    }
  }
#pragma unroll
  for (int nf = 0; nf < 5; ++nf) {
    int j = nf * 16 + (lane & 15);
    if (j < 69) {
      float bs = bias2[j];
      int a, ch2;
      if (j < 24) { a = j >> 3; ch2 = j & 7; }
      else { int jj = j - 24; a = jj / 15; ch2 = 10 + (jj % 15); }
#pragma unroll
      for (int q = 0; q < 4; ++q) {
        int m  = m0 + wid * 16 + ((lane >> 4) << 2) + q;
        int bb = m >> 12, hw = m & 4095;
        out[(((size_t)(bb * 3 + a)) * 25 + ch2) * 4096 + hw] = acc[nf][q] + bs;
      }
    }
  }
}

extern "C" void kernel_launch(void* const* d_in, const int* in_sizes, int n_in,
                              void* d_out, int out_size, void* d_ws, size_t ws_size,
                              hipStream_t stream) {
  const float* x      = (const float*)d_in[0];
  const float* w_conf = (const float*)d_in[1];
  const float* b_conf = (const float*)d_in[2];
  const float* w_om   = (const float*)d_in[3];
  const float* b_om   = (const float*)d_in[4];
  const float* w_dloc = (const float*)d_in[5];
  const float* g_loc  = (const float*)d_in[6];
  const float* be_loc = (const float*)d_in[7];
  const float* m_loc  = (const float*)d_in[8];
  const float* v_loc  = (const float*)d_in[9];
  const float* w_locx = (const float*)d_in[10];
  const float* b_locx = (const float*)d_in[11];
  const float* w_dcla = (const float*)d_in[12];
  const float* g_cla  = (const float*)d_in[13];
  const float* be_cla = (const float*)d_in[14];
  const float* m_cla  = (const float*)d_in[15];
  const float* v_cla  = (const float*)d_in[16];
  const float* w_clax = (const float*)d_in[17];
  const float* b_clax = (const float*)d_in[18];
  float* out = (float*)d_out;

  char* ws = (char*)d_ws;
  size_t off = 0;
  unsigned short* xTp = (unsigned short*)(ws + off); off += (size_t)8 * HP * HP * C_ * 2;
  unsigned short* wT  = (unsigned short*)(ws + off); off += (size_t)512 * K_ * 2;
  unsigned short* W2t = (unsigned short*)(ws + off); off += (size_t)80 * 512 * 2;
  unsigned short* wB  = (unsigned short*)(ws + off); off += (size_t)48 * 256 * 2;
  float* bnA   = (float*)(ws + off); off += 512 * 4;
  float* bnB   = (float*)(ws + off); off += 512 * 4;
  float* bias2 = (float*)(ws + off); off += 128 * 4;
  unsigned int* rec_i = (unsigned int*)(ws + off); off += (size_t)294912 * 4;
  float4* rec_w       = (float4*)(ws + off);       off += (size_t)294912 * 16;
  unsigned short* y   = (unsigned short*)(ws + off); off += (size_t)32768 * 512 * 2;

  k_transpose<<<2048, 256, 0, stream>>>(x, xTp);
  {
    int total = 512 * K_ + 80 * 512 + 48 * 256 + 512 + 80;
    k_prep<<<(total + 255) / 256, 256, 0, stream>>>(w_dloc, w_dcla, w_locx, w_clax,
        g_loc, be_loc, m_loc, v_loc, g_cla, be_cla, m_cla, v_cla, b_locx, b_clax,
        w_om, w_conf, wT, W2t, wB, bnA, bnB, bias2);
  }
  k_offsets<<<256, 256, 0, stream>>>(xTp, wB, b_om, b_conf, rec_i, rec_w, out);
  k_deform_gemm<<<1024, 256, 0, stream>>>(xTp, wT, rec_i, rec_w, bnA, bnB, y);
  k_final<<<512, 256, 0, stream>>>(y, W2t, bias2, out);
}